// Round 5
// baseline (844.674 us; speedup 1.0000x reference)
//
#include <hip/hip_runtime.h>
#include <hip/hip_fp16.h>
#include <math.h>

#define HEADS 2
#define FDIM 128
#define INDIM 64
#define ODIM 32
#define NEG_SLOPE 0.2f
#define BSH 7                 // bucket = dst >> 7  (128 dsts/bucket)
#define BW  128

typedef _Float16 f16x8 __attribute__((ext_vector_type(8)));
typedef float f32x4 __attribute__((ext_vector_type(4)));
union H8 { uint4 u; f16x8 v; __half2 h2[4]; };
union H4 { uint2 u; __half2 h2[2]; };

__device__ __forceinline__ float elu1(float v) { return v > 0.f ? v : __expf(v) - 1.f; }

#define MFMA16(a, b, c) __builtin_amdgcn_mfma_f32_16x16x32_f16((a), (b), (c), 0, 0, 0)

// ---------------- CSR build: bucketed counting sort ----------------
__global__ void k_zero(int* __restrict__ p, int n) {
    int i = blockIdx.x * blockDim.x + threadIdx.x;
    if (i < n) p[i] = 0;
}

// per-block LDS histogram of buckets -> few global atomics
__global__ __launch_bounds__(256) void k_hist(const int* __restrict__ ei, int E_,
                                              int* __restrict__ bcnt, int nb, int ept) {
    __shared__ int h[512];
    int t = threadIdx.x;
    for (int i = t; i < nb; i += 256) h[i] = 0;
    __syncthreads();
    int e0 = blockIdx.x * ept;
    int e1 = min(E_, e0 + ept);
    for (int e = e0 + t; e < e1; e += 256)
        atomicAdd(&h[ei[E_ + e] >> BSH], 1);
    __syncthreads();
    for (int i = t; i < nb; i += 256) {
        int v = h[i];
        if (v) atomicAdd(&bcnt[i], v);
    }
}

// exclusive scan of bcnt[0..nb) -> bstart[0..nb], bcur copy (1 block, 512 thr)
__global__ __launch_bounds__(512) void k_scan_b(const int* __restrict__ bcnt,
                                                int* __restrict__ bstart,
                                                int* __restrict__ bcur, int nb) {
    __shared__ int sc[512];
    int t = threadIdx.x;
    int v = (t < nb) ? bcnt[t] : 0;
    sc[t] = v;
    __syncthreads();
    for (int o = 1; o < 512; o <<= 1) {
        int add = (t >= o) ? sc[t - o] : 0;
        __syncthreads();
        sc[t] += add;
        __syncthreads();
    }
    if (t <= nb) {
        int ex = sc[t] - v;            // exclusive (for t==nb: total)
        bstart[t] = ex;
        if (t < nb) bcur[t] = ex;
    }
}

// bin edges into bucket-contiguous ebuf; XCD-partitioned to keep each bucket's
// write frontier in one XCD's L2 (blockIdx&7 ~ XCD round-robin; perf-only)
__global__ __launch_bounds__(256) void k_scatter_b(const int* __restrict__ ei, int E_,
                                                   int* __restrict__ bcur,
                                                   int2* __restrict__ ebuf,
                                                   int slice) {
    int xcd = blockIdx.x & 7;
    int g = blockIdx.x >> 3;
    int e0 = g * slice;
    int e1 = min(E_, e0 + slice);
    for (int e = e0 + threadIdx.x; e < e1; e += 256) {
        int d = ei[E_ + e];
        int b = d >> BSH;
        if ((b & 7) == xcd) {
            int slot = atomicAdd(&bcur[b], 1);
            ebuf[slot] = make_int2(ei[e], d);
        }
    }
}

// one block per bucket: LDS hist+scan of 128 local dsts -> offs + ranked fill
__global__ __launch_bounds__(256) void k_bfill(const int2* __restrict__ ebuf,
                                               const int* __restrict__ bstart,
                                               int* __restrict__ offs,
                                               int* __restrict__ csr_src, int n) {
    __shared__ int hist[BW], sc[BW], pcur[BW];
    int b = blockIdx.x;
    int t = threadIdx.x;
    int base = bstart[b];
    int cnt = bstart[b + 1] - base;
    int d0 = b << BSH;
    if (t < BW) hist[t] = 0;
    __syncthreads();
    for (int i = t; i < cnt; i += 256)
        atomicAdd(&hist[ebuf[base + i].y - d0], 1);
    __syncthreads();
    int v = (t < BW) ? hist[t] : 0;
    if (t < BW) sc[t] = v;
    __syncthreads();
    for (int o = 1; o < BW; o <<= 1) {
        int add = (t < BW && t >= o) ? sc[t - o] : 0;
        __syncthreads();
        if (t < BW) sc[t] += add;
        __syncthreads();
    }
    if (t < BW) {
        int abspos = base + sc[t] - v;   // exclusive
        pcur[t] = abspos;
        if (d0 + t < n) offs[d0 + t] = abspos;
    }
    __syncthreads();
    for (int i = t; i < cnt; i += 256) {
        int2 e = ebuf[base + i];
        int slot = atomicAdd(&pcur[e.y - d0], 1);
        csr_src[slot] = e.x;
    }
}

// ---------- weight precompute ----------
__global__ __launch_bounds__(128) void k_fuse_w(
    const float* __restrict__ W0,
    const float* __restrict__ fcw0, const float* __restrict__ fcb0, const float* __restrict__ W1,
    const float* __restrict__ fcw1, const float* __restrict__ fcb1,
    const float* __restrict__ out_w, const float* __restrict__ out_b,
    __half* __restrict__ W0T, __half* __restrict__ WfT, float* __restrict__ bf,
    __half* __restrict__ WfoT, float* __restrict__ bfo)
{
    int b = blockIdx.x, c = threadIdx.x;
    if (b < 128) {
        float acc = 0.f;
        for (int j = 0; j < 64; ++j) acc = fmaf(fcw0[b * 64 + j], W1[j * 128 + c], acc);
        WfT[c * 128 + b] = __float2half(acc);
    } else if (b == 128) {
        float acc = 0.f;
        for (int j = 0; j < 64; ++j) acc = fmaf(fcb0[j], W1[j * 128 + c], acc);
        bf[c] = acc;
    } else if (b < 257) {
        int k = b - 129;
        if (c < 32) {
            float acc = 0.f;
            for (int j = 0; j < 64; ++j) acc = fmaf(fcw1[k * 64 + j], out_w[j * 32 + c], acc);
            WfoT[c * 128 + k] = __float2half(acc);
        }
    } else if (b == 257) {
        if (c < 32) {
            float acc = 0.f;
            for (int j = 0; j < 64; ++j) acc = fmaf(fcb1[j], out_w[j * 32 + c], acc);
            bfo[c] = acc + out_b[c];
        }
    } else {
        int k = b - 258;
        W0T[c * 64 + k] = __float2half(W0[k * 128 + c]);
    }
}

// ---------- layer-1: xl = x@W0 (fp16 out) + a_src/a_dst, MFMA ----------
__global__ __launch_bounds__(256, 2) void k_mm_att1(
    const float* __restrict__ x, const __half* __restrict__ w0t,
    const float* __restrict__ att_src, const float* __restrict__ att_dst,
    __half* __restrict__ xl, float* __restrict__ a_src, float* __restrict__ a_dst,
    int n, int ntiles, int nwaves)
{
    int lane = threadIdx.x & 63;
    int wid = blockIdx.x * 4 + (threadIdx.x >> 6);
    int m = lane & 15, q = lane >> 4;

    H8 A[8][2];
    #pragma unroll
    for (int nt = 0; nt < 8; ++nt)
        #pragma unroll
        for (int kt = 0; kt < 2; ++kt)
            A[nt][kt].u = *(const uint4*)(w0t + (size_t)(nt * 16 + m) * 64 + kt * 32 + q * 8);

    for (int t = wid; t < ntiles; t += nwaves) {
        int rb = t * 16;
        int row = rb + m; if (row >= n) row = n - 1;
        H8 B[2];
        #pragma unroll
        for (int kt = 0; kt < 2; ++kt) {
            const float4* p = (const float4*)(x + (size_t)row * 64 + kt * 32 + q * 8);
            float4 p0 = p[0], p1 = p[1];
            B[kt].h2[0] = __floats2half2_rn(p0.x, p0.y);
            B[kt].h2[1] = __floats2half2_rn(p0.z, p0.w);
            B[kt].h2[2] = __floats2half2_rn(p1.x, p1.y);
            B[kt].h2[3] = __floats2half2_rn(p1.z, p1.w);
        }
        f32x4 acc[8];
        #pragma unroll
        for (int nt = 0; nt < 8; ++nt) {
            acc[nt] = {0.f, 0.f, 0.f, 0.f};
            acc[nt] = MFMA16(A[nt][0].v, B[0].v, acc[nt]);
            acc[nt] = MFMA16(A[nt][1].v, B[1].v, acc[nt]);
        }
        float ps0 = 0.f, ps1 = 0.f, pd0 = 0.f, pd1 = 0.f;
        bool ok = (rb + m) < n;
        #pragma unroll
        for (int nt = 0; nt < 8; ++nt) {
            float4 asv = *(const float4*)(att_src + nt * 16 + q * 4);
            float4 adv = *(const float4*)(att_dst + nt * 16 + q * 4);
            f32x4 d = acc[nt];
            H4 pk;
            pk.h2[0] = __floats2half2_rn(d[0], d[1]);
            pk.h2[1] = __floats2half2_rn(d[2], d[3]);
            if (ok) *(uint2*)(xl + (size_t)(rb + m) * 128 + nt * 16 + q * 4) = pk.u;
            float cs = d[0] * asv.x + d[1] * asv.y + d[2] * asv.z + d[3] * asv.w;
            float cd = d[0] * adv.x + d[1] * adv.y + d[2] * adv.z + d[3] * adv.w;
            if (nt < 4) { ps0 += cs; pd0 += cd; } else { ps1 += cs; pd1 += cd; }
        }
        ps0 += __shfl_xor(ps0, 16, 64); ps0 += __shfl_xor(ps0, 32, 64);
        ps1 += __shfl_xor(ps1, 16, 64); ps1 += __shfl_xor(ps1, 32, 64);
        pd0 += __shfl_xor(pd0, 16, 64); pd0 += __shfl_xor(pd0, 32, 64);
        pd1 += __shfl_xor(pd1, 16, 64); pd1 += __shfl_xor(pd1, 32, 64);
        if (lane < 16 && ok) {
            *(float2*)(a_src + (size_t)(rb + m) * 2) = make_float2(ps0, ps1);
            *(float2*)(a_dst + (size_t)(rb + m) * 2) = make_float2(pd0, pd1);
        }
    }
}

// ---------- layer-2: xl = elu(gat)@Wf + bf (fp16 out) + a_src/a_dst ----------
__global__ __launch_bounds__(256, 2) void k_mm_att2(
    const float* __restrict__ g, const __half* __restrict__ wft, const float* __restrict__ bf,
    const float* __restrict__ att_src, const float* __restrict__ att_dst,
    __half* __restrict__ xl, float* __restrict__ a_src, float* __restrict__ a_dst,
    int n, int ntiles, int nwaves)
{
    int lane = threadIdx.x & 63;
    int wid = blockIdx.x * 4 + (threadIdx.x >> 6);
    int m = lane & 15, q = lane >> 4;

    H8 A[8][4];
    #pragma unroll
    for (int nt = 0; nt < 8; ++nt)
        #pragma unroll
        for (int kt = 0; kt < 4; ++kt)
            A[nt][kt].u = *(const uint4*)(wft + (size_t)(nt * 16 + m) * 128 + kt * 32 + q * 8);

    for (int t = wid; t < ntiles; t += nwaves) {
        int rb = t * 16;
        int row = rb + m; if (row >= n) row = n - 1;
        H8 B[4];
        #pragma unroll
        for (int kt = 0; kt < 4; ++kt) {
            const float4* p = (const float4*)(g + (size_t)row * 128 + kt * 32 + q * 8);
            float4 p0 = p[0], p1 = p[1];
            B[kt].h2[0] = __floats2half2_rn(elu1(p0.x), elu1(p0.y));
            B[kt].h2[1] = __floats2half2_rn(elu1(p0.z), elu1(p0.w));
            B[kt].h2[2] = __floats2half2_rn(elu1(p1.x), elu1(p1.y));
            B[kt].h2[3] = __floats2half2_rn(elu1(p1.z), elu1(p1.w));
        }
        f32x4 acc[8];
        #pragma unroll
        for (int nt = 0; nt < 8; ++nt) {
            acc[nt] = {0.f, 0.f, 0.f, 0.f};
            #pragma unroll
            for (int kt = 0; kt < 4; ++kt)
                acc[nt] = MFMA16(A[nt][kt].v, B[kt].v, acc[nt]);
        }
        float ps0 = 0.f, ps1 = 0.f, pd0 = 0.f, pd1 = 0.f;
        bool ok = (rb + m) < n;
        #pragma unroll
        for (int nt = 0; nt < 8; ++nt) {
            float4 bfv = *(const float4*)(bf + nt * 16 + q * 4);
            float4 asv = *(const float4*)(att_src + nt * 16 + q * 4);
            float4 adv = *(const float4*)(att_dst + nt * 16 + q * 4);
            f32x4 d = acc[nt];
            d[0] += bfv.x; d[1] += bfv.y; d[2] += bfv.z; d[3] += bfv.w;
            H4 pk;
            pk.h2[0] = __floats2half2_rn(d[0], d[1]);
            pk.h2[1] = __floats2half2_rn(d[2], d[3]);
            if (ok) *(uint2*)(xl + (size_t)(rb + m) * 128 + nt * 16 + q * 4) = pk.u;
            float cs = d[0] * asv.x + d[1] * asv.y + d[2] * asv.z + d[3] * asv.w;
            float cd = d[0] * adv.x + d[1] * adv.y + d[2] * adv.z + d[3] * adv.w;
            if (nt < 4) { ps0 += cs; pd0 += cd; } else { ps1 += cs; pd1 += cd; }
        }
        ps0 += __shfl_xor(ps0, 16, 64); ps0 += __shfl_xor(ps0, 32, 64);
        ps1 += __shfl_xor(ps1, 16, 64); ps1 += __shfl_xor(ps1, 32, 64);
        pd0 += __shfl_xor(pd0, 16, 64); pd0 += __shfl_xor(pd0, 32, 64);
        pd1 += __shfl_xor(pd1, 16, 64); pd1 += __shfl_xor(pd1, 32, 64);
        if (lane < 16 && ok) {
            *(float2*)(a_src + (size_t)(rb + m) * 2) = make_float2(ps0, ps1);
            *(float2*)(a_dst + (size_t)(rb + m) * 2) = make_float2(pd0, pd1);
        }
    }
}

// ---------- gather: 1 wave/dst, 4 edges/iter, fp16 xl ----------
__global__ __launch_bounds__(256, 4) void k_gather(
    const int* __restrict__ offs, const int* __restrict__ csr_src, int E_,
    const __half* __restrict__ xl, const float* __restrict__ a_src,
    const float* __restrict__ a_dst, const float* __restrict__ bias,
    float* __restrict__ out, int n)
{
    int t = threadIdx.x;
    int lane = t & 63;
    int d = blockIdx.x * 4 + (t >> 6);
    if (d >= n) return;
    int eh = lane >> 4;
    int cq = lane & 15;
    int h = cq >> 3;
    float ad = a_dst[d * 2 + h];
    const float4* bp = (const float4*)(bias + cq * 8);
    float4 b0 = bp[0], b1 = bp[1];
    int start = offs[d];
    int end = (d + 1 < n) ? offs[d + 1] : E_;
    float acc[8] = {0.f, 0.f, 0.f, 0.f, 0.f, 0.f, 0.f, 0.f};
    float den = 0.f;
    for (int j0 = start; j0 < end; j0 += 4) {
        int j = j0 + eh;
        bool valid = j < end;
        int s = valid ? csr_src[j] : d;
        float a = a_src[s * 2 + h] + ad;
        a = (a >= 0.f) ? a : NEG_SLOPE * a;
        float w = valid ? __expf(a) : 0.f;
        float4 raw = *(const float4*)(xl + (size_t)s * 128 + cq * 8);
        __half2* hp = (__half2*)&raw;
        float2 f0 = __half22float2(hp[0]);
        float2 f1 = __half22float2(hp[1]);
        float2 f2 = __half22float2(hp[2]);
        float2 f3 = __half22float2(hp[3]);
        acc[0] = fmaf(w, f0.x, acc[0]); acc[1] = fmaf(w, f0.y, acc[1]);
        acc[2] = fmaf(w, f1.x, acc[2]); acc[3] = fmaf(w, f1.y, acc[3]);
        acc[4] = fmaf(w, f2.x, acc[4]); acc[5] = fmaf(w, f2.y, acc[5]);
        acc[6] = fmaf(w, f3.x, acc[6]); acc[7] = fmaf(w, f3.y, acc[7]);
        den += w;
    }
    if (eh == 0) {
        float a = a_src[d * 2 + h] + ad;
        a = (a >= 0.f) ? a : NEG_SLOPE * a;
        float w = __expf(a);
        float4 raw = *(const float4*)(xl + (size_t)d * 128 + cq * 8);
        __half2* hp = (__half2*)&raw;
        float2 f0 = __half22float2(hp[0]);
        float2 f1 = __half22float2(hp[1]);
        float2 f2 = __half22float2(hp[2]);
        float2 f3 = __half22float2(hp[3]);
        acc[0] = fmaf(w, f0.x, acc[0]); acc[1] = fmaf(w, f0.y, acc[1]);
        acc[2] = fmaf(w, f1.x, acc[2]); acc[3] = fmaf(w, f1.y, acc[3]);
        acc[4] = fmaf(w, f2.x, acc[4]); acc[5] = fmaf(w, f2.y, acc[5]);
        acc[6] = fmaf(w, f3.x, acc[6]); acc[7] = fmaf(w, f3.y, acc[7]);
        den += w;
    }
    #pragma unroll
    for (int i = 0; i < 8; ++i) {
        acc[i] += __shfl_xor(acc[i], 16, 64);
        acc[i] += __shfl_xor(acc[i], 32, 64);
    }
    den += __shfl_xor(den, 16, 64);
    den += __shfl_xor(den, 32, 64);
    if (eh == 0) {
        float inv = 1.f / (den + 1e-16f);
        float4 o0 = make_float4(fmaf(acc[0], inv, b0.x), fmaf(acc[1], inv, b0.y),
                                fmaf(acc[2], inv, b0.z), fmaf(acc[3], inv, b0.w));
        float4 o1 = make_float4(fmaf(acc[4], inv, b1.x), fmaf(acc[5], inv, b1.y),
                                fmaf(acc[6], inv, b1.z), fmaf(acc[7], inv, b1.w));
        float4* op = (float4*)(out + (size_t)d * 128 + cq * 8);
        op[0] = o0; op[1] = o1;
    }
}

// ---------- head: softmax(elu(gat2)@Wfo + bfo + gumbel), MFMA ----------
__global__ __launch_bounds__(256, 2) void k_mm_final(
    const float* __restrict__ g, const __half* __restrict__ wfot, const float* __restrict__ bfo,
    const float* __restrict__ gu, float* __restrict__ out, int n, int ntiles, int nwaves)
{
    int lane = threadIdx.x & 63;
    int wid = blockIdx.x * 4 + (threadIdx.x >> 6);
    int m = lane & 15, q = lane >> 4;

    H8 A[2][4];
    #pragma unroll
    for (int nt = 0; nt < 2; ++nt)
        #pragma unroll
        for (int kt = 0; kt < 4; ++kt)
            A[nt][kt].u = *(const uint4*)(wfot + (size_t)(nt * 16 + m) * 128 + kt * 32 + q * 8);

    for (int t = wid; t < ntiles; t += nwaves) {
        int rb = t * 16;
        int row = rb + m; if (row >= n) row = n - 1;
        H8 B[4];
        #pragma unroll
        for (int kt = 0; kt < 4; ++kt) {
            const float4* p = (const float4*)(g + (size_t)row * 128 + kt * 32 + q * 8);
            float4 p0 = p[0], p1 = p[1];
            B[kt].h2[0] = __floats2half2_rn(elu1(p0.x), elu1(p0.y));
            B[kt].h2[1] = __floats2half2_rn(elu1(p0.z), elu1(p0.w));
            B[kt].h2[2] = __floats2half2_rn(elu1(p1.x), elu1(p1.y));
            B[kt].h2[3] = __floats2half2_rn(elu1(p1.z), elu1(p1.w));
        }
        f32x4 acc[2];
        #pragma unroll
        for (int nt = 0; nt < 2; ++nt) {
            acc[nt] = {0.f, 0.f, 0.f, 0.f};
            #pragma unroll
            for (int kt = 0; kt < 4; ++kt)
                acc[nt] = MFMA16(A[nt][kt].v, B[kt].v, acc[nt]);
        }
        float z[8];
        #pragma unroll
        for (int nt = 0; nt < 2; ++nt) {
            float4 bv = *(const float4*)(bfo + nt * 16 + q * 4);
            float4 uv = *(const float4*)(gu + (size_t)row * 32 + nt * 16 + q * 4);
            z[nt * 4 + 0] = acc[nt][0] + bv.x - __logf(-__logf(uv.x + 1e-20f) + 1e-20f);
            z[nt * 4 + 1] = acc[nt][1] + bv.y - __logf(-__logf(uv.y + 1e-20f) + 1e-20f);
            z[nt * 4 + 2] = acc[nt][2] + bv.z - __logf(-__logf(uv.z + 1e-20f) + 1e-20f);
            z[nt * 4 + 3] = acc[nt][3] + bv.w - __logf(-__logf(uv.w + 1e-20f) + 1e-20f);
        }
        float mx = z[0];
        #pragma unroll
        for (int i = 1; i < 8; ++i) mx = fmaxf(mx, z[i]);
        mx = fmaxf(mx, __shfl_xor(mx, 16, 64));
        mx = fmaxf(mx, __shfl_xor(mx, 32, 64));
        float sum = 0.f;
        #pragma unroll
        for (int i = 0; i < 8; ++i) { z[i] = __expf(z[i] - mx); sum += z[i]; }
        sum += __shfl_xor(sum, 16, 64);
        sum += __shfl_xor(sum, 32, 64);
        float inv = 1.f / sum;
        if (rb + m < n) {
            #pragma unroll
            for (int nt = 0; nt < 2; ++nt) {
                float4 o = make_float4(z[nt * 4 + 0] * inv, z[nt * 4 + 1] * inv,
                                       z[nt * 4 + 2] * inv, z[nt * 4 + 3] * inv);
                *(float4*)(out + (size_t)(rb + m) * 32 + nt * 16 + q * 4) = o;
            }
        }
    }
}

extern "C" void kernel_launch(void* const* d_in, const int* in_sizes, int n_in,
                              void* d_out, int out_size, void* d_ws, size_t ws_size,
                              hipStream_t stream) {
    const float* x        = (const float*)d_in[0];
    const int*   ei       = (const int*)  d_in[1];
    const float* W0       = (const float*)d_in[2];
    const float* att_src0 = (const float*)d_in[3];
    const float* att_dst0 = (const float*)d_in[4];
    const float* bias0    = (const float*)d_in[5];
    const float* fcw0     = (const float*)d_in[6];
    const float* fcb0     = (const float*)d_in[7];
    const float* W1       = (const float*)d_in[8];
    const float* att_src1 = (const float*)d_in[9];
    const float* att_dst1 = (const float*)d_in[10];
    const float* bias1    = (const float*)d_in[11];
    const float* fcw1     = (const float*)d_in[12];
    const float* fcb1     = (const float*)d_in[13];
    const float* out_w    = (const float*)d_in[14];
    const float* out_b    = (const float*)d_in[15];
    const float* gu       = (const float*)d_in[16];

    const int N_ = in_sizes[0] / INDIM;
    const int E_ = in_sizes[1] / 2;
    const int NB = (N_ + BW - 1) / BW;            // buckets

    float* ws = (float*)d_ws;
    size_t off = 0;
    __half* xl  = (__half*)(ws + off); off += (size_t)N_ * 64;
    float* gat   = ws + off; off += (size_t)N_ * FDIM;
    float* a_src = ws + off; off += (size_t)N_ * HEADS;
    float* a_dst = ws + off; off += (size_t)N_ * HEADS;
    __half* W0T  = (__half*)(ws + off); off += 128 * 64 / 2;
    __half* WfT  = (__half*)(ws + off); off += 128 * 128 / 2;
    __half* WfoT = (__half*)(ws + off); off += 32 * 128 / 2;
    float* bf    = ws + off; off += 128;
    float* bfo   = ws + off; off += 32;
    int* bcnt    = (int*)(ws + off); off += NB + 1;
    int* bstart  = (int*)(ws + off); off += NB + 1;
    int* bcur    = (int*)(ws + off); off += NB + 1;
    int* offs    = (int*)(ws + off); off += N_;
    int* csr_src = (int*)(ws + off); off += E_;
    if (off & 1) off += 1;                        // 8B-align ebuf
    int2* ebuf   = (int2*)(ws + off); off += (size_t)E_ * 2;

    const int B = 256;
    dim3 blk(B);
    int g_gath = (N_ + 3) / 4;
    int ntiles = (N_ + 15) / 16;
    int GMM    = 384;
    int nwaves = GMM * 4;
    int ept    = 4096;
    int g_hist = (E_ + ept - 1) / ept;
    int NG     = 64;
    int slice  = (E_ + NG - 1) / NG;

    // ---- CSR build: bucketed counting sort ----
    k_zero      <<<(NB + 256) / 256, blk, 0, stream>>>(bcnt, NB + 1);
    k_hist      <<<g_hist, blk, 0, stream>>>(ei, E_, bcnt, NB, ept);
    k_scan_b    <<<1, dim3(512), 0, stream>>>(bcnt, bstart, bcur, NB);
    k_scatter_b <<<NG * 8, blk, 0, stream>>>(ei, E_, bcur, ebuf, slice);
    k_bfill     <<<NB, blk, 0, stream>>>(ebuf, bstart, offs, csr_src, N_);
    k_fuse_w    <<<322, dim3(128), 0, stream>>>(W0, fcw0, fcb0, W1, fcw1, fcb1, out_w, out_b,
                                                W0T, WfT, bf, WfoT, bfo);

    // ---- layer 1 ----
    k_mm_att1 <<<GMM,    blk, 0, stream>>>(x, W0T, att_src0, att_dst0, xl, a_src, a_dst,
                                           N_, ntiles, nwaves);
    k_gather  <<<g_gath, blk, 0, stream>>>(offs, csr_src, E_, xl, a_src, a_dst, bias0, gat, N_);

    // ---- layer 2 (fc0 fused via WfT) ----
    k_mm_att2 <<<GMM,    blk, 0, stream>>>(gat, WfT, bf, att_src1, att_dst1, xl, a_src, a_dst,
                                           N_, ntiles, nwaves);
    k_gather  <<<g_gath, blk, 0, stream>>>(offs, csr_src, E_, xl, a_src, a_dst, bias1, gat, N_);

    // ---- head (fc1 + out fused via WfoT) ----
    k_mm_final <<<GMM,   blk, 0, stream>>>(gat, WfoT, bfo, gu, (float*)d_out, N_, ntiles, nwaves);
}

// Round 6
// 297.018 us; speedup vs baseline: 2.8438x; 2.8438x over previous
//
#include <hip/hip_runtime.h>
#include <hip/hip_fp16.h>
#include <math.h>

#define HEADS 2
#define FDIM 128
#define INDIM 64
#define ODIM 32
#define NEG_SLOPE 0.2f
#define BSH 7                 // bucket = dst >> 7  (128 dsts/bucket)
#define BW  128
#define NBLK 128              // radix pass blocks

typedef _Float16 f16x8 __attribute__((ext_vector_type(8)));
typedef float f32x4 __attribute__((ext_vector_type(4)));
union H8 { uint4 u; f16x8 v; __half2 h2[4]; };
union H4 { uint2 u; __half2 h2[2]; };

__device__ __forceinline__ float elu1(float v) { return v > 0.f ? v : __expf(v) - 1.f; }

#define MFMA16(a, b, c) __builtin_amdgcn_mfma_f32_16x16x32_f16((a), (b), (c), 0, 0, 0)

// ---------------- CSR build: two-pass radix by bucket, LDS-atomics only ----------------
// pass 1: per-block LDS histogram -> cnt[b][blk]  (no global atomics)
__global__ __launch_bounds__(256) void k_hist2(const int* __restrict__ ei, int E_,
                                               int* __restrict__ cnt, int nb, int epb) {
    __shared__ int h[512];
    int t = threadIdx.x, blk = blockIdx.x;
    for (int i = t; i < nb; i += 256) h[i] = 0;
    __syncthreads();
    int e0 = blk * epb, e1 = min(E_, e0 + epb);
    for (int e = e0 + t; e < e1; e += 256)
        atomicAdd(&h[ei[E_ + e] >> BSH], 1);
    __syncthreads();
    for (int i = t; i < nb; i += 256) cnt[i * NBLK + blk] = h[i];
}

// scan: bucket totals -> bstart (exclusive), running bases base[b][blk]
__global__ __launch_bounds__(512) void k_scanb(const int* __restrict__ cnt,
                                               int* __restrict__ bstart,
                                               int* __restrict__ base, int nb, int E_) {
    __shared__ int sc[512];
    int t = threadIdx.x;
    int tot = 0;
    if (t < nb)
        for (int k = 0; k < NBLK; ++k) tot += cnt[t * NBLK + k];
    sc[t] = tot;
    __syncthreads();
    for (int o = 1; o < 512; o <<= 1) {
        int add = (t >= o) ? sc[t - o] : 0;
        __syncthreads();
        sc[t] += add;
        __syncthreads();
    }
    int ex = sc[t] - tot;
    if (t < nb) {
        bstart[t] = ex;
        int run = ex;
        for (int k = 0; k < NBLK; ++k) {
            base[t * NBLK + k] = run;
            run += cnt[t * NBLK + k];
        }
    }
    if (t == 0) bstart[nb] = E_;
}

// pass 2: place edges; LDS frontier counters seeded from base[b][blk]
__global__ __launch_bounds__(256) void k_scatter2(const int* __restrict__ ei, int E_,
                                                  const int* __restrict__ base,
                                                  unsigned* __restrict__ ebuf,
                                                  int nb, int epb) {
    __shared__ int pcur[512];
    int t = threadIdx.x, blk = blockIdx.x;
    for (int i = t; i < nb; i += 256) pcur[i] = base[i * NBLK + blk];
    __syncthreads();
    int e0 = blk * epb, e1 = min(E_, e0 + epb);
    for (int e = e0 + t; e < e1; e += 256) {
        int s = ei[e], d = ei[E_ + e];
        int slot = atomicAdd(&pcur[d >> BSH], 1);
        ebuf[slot] = ((unsigned)(d & (BW - 1)) << 25) | (unsigned)s;
    }
}

// one block per bucket: LDS hist+scan of 128 local dsts -> offs + ranked fill
__global__ __launch_bounds__(256) void k_bfill(const unsigned* __restrict__ ebuf,
                                               const int* __restrict__ bstart,
                                               int* __restrict__ offs,
                                               int* __restrict__ csr_src, int n) {
    __shared__ int hist[BW], sc[BW], pcur[BW];
    int b = blockIdx.x;
    int t = threadIdx.x;
    int base_ = bstart[b];
    int cnt = bstart[b + 1] - base_;
    int d0 = b << BSH;
    if (t < BW) hist[t] = 0;
    __syncthreads();
    for (int i = t; i < cnt; i += 256)
        atomicAdd(&hist[ebuf[base_ + i] >> 25], 1);
    __syncthreads();
    int v = (t < BW) ? hist[t] : 0;
    if (t < BW) sc[t] = v;
    __syncthreads();
    for (int o = 1; o < BW; o <<= 1) {
        int add = (t < BW && t >= o) ? sc[t - o] : 0;
        __syncthreads();
        if (t < BW) sc[t] += add;
        __syncthreads();
    }
    if (t < BW) {
        int abspos = base_ + sc[t] - v;   // exclusive
        pcur[t] = abspos;
        if (d0 + t < n) offs[d0 + t] = abspos;
    }
    __syncthreads();
    for (int i = t; i < cnt; i += 256) {
        unsigned u = ebuf[base_ + i];
        int slot = atomicAdd(&pcur[u >> 25], 1);
        csr_src[slot] = (int)(u & 0x1FFFFFFu);
    }
}

// ---------- weight precompute ----------
__global__ __launch_bounds__(128) void k_fuse_w(
    const float* __restrict__ W0,
    const float* __restrict__ fcw0, const float* __restrict__ fcb0, const float* __restrict__ W1,
    const float* __restrict__ fcw1, const float* __restrict__ fcb1,
    const float* __restrict__ out_w, const float* __restrict__ out_b,
    __half* __restrict__ W0T, __half* __restrict__ WfT, float* __restrict__ bf,
    __half* __restrict__ WfoT, float* __restrict__ bfo)
{
    int b = blockIdx.x, c = threadIdx.x;
    if (b < 128) {
        float acc = 0.f;
        for (int j = 0; j < 64; ++j) acc = fmaf(fcw0[b * 64 + j], W1[j * 128 + c], acc);
        WfT[c * 128 + b] = __float2half(acc);
    } else if (b == 128) {
        float acc = 0.f;
        for (int j = 0; j < 64; ++j) acc = fmaf(fcb0[j], W1[j * 128 + c], acc);
        bf[c] = acc;
    } else if (b < 257) {
        int k = b - 129;
        if (c < 32) {
            float acc = 0.f;
            for (int j = 0; j < 64; ++j) acc = fmaf(fcw1[k * 64 + j], out_w[j * 32 + c], acc);
            WfoT[c * 128 + k] = __float2half(acc);
        }
    } else if (b == 257) {
        if (c < 32) {
            float acc = 0.f;
            for (int j = 0; j < 64; ++j) acc = fmaf(fcb1[j], out_w[j * 32 + c], acc);
            bfo[c] = acc + out_b[c];
        }
    } else {
        int k = b - 258;
        W0T[c * 64 + k] = __float2half(W0[k * 128 + c]);
    }
}

// ---------- layer-1: xl = x@W0 (fp16 out) + a_src/a_dst, MFMA ----------
__global__ __launch_bounds__(256, 2) void k_mm_att1(
    const float* __restrict__ x, const __half* __restrict__ w0t,
    const float* __restrict__ att_src, const float* __restrict__ att_dst,
    __half* __restrict__ xl, float* __restrict__ a_src, float* __restrict__ a_dst,
    int n, int ntiles, int nwaves)
{
    int lane = threadIdx.x & 63;
    int wid = blockIdx.x * 4 + (threadIdx.x >> 6);
    int m = lane & 15, q = lane >> 4;

    H8 A[8][2];
    #pragma unroll
    for (int nt = 0; nt < 8; ++nt)
        #pragma unroll
        for (int kt = 0; kt < 2; ++kt)
            A[nt][kt].u = *(const uint4*)(w0t + (size_t)(nt * 16 + m) * 64 + kt * 32 + q * 8);

    for (int t = wid; t < ntiles; t += nwaves) {
        int rb = t * 16;
        int row = rb + m; if (row >= n) row = n - 1;
        H8 B[2];
        #pragma unroll
        for (int kt = 0; kt < 2; ++kt) {
            const float4* p = (const float4*)(x + (size_t)row * 64 + kt * 32 + q * 8);
            float4 p0 = p[0], p1 = p[1];
            B[kt].h2[0] = __floats2half2_rn(p0.x, p0.y);
            B[kt].h2[1] = __floats2half2_rn(p0.z, p0.w);
            B[kt].h2[2] = __floats2half2_rn(p1.x, p1.y);
            B[kt].h2[3] = __floats2half2_rn(p1.z, p1.w);
        }
        f32x4 acc[8];
        #pragma unroll
        for (int nt = 0; nt < 8; ++nt) {
            acc[nt] = {0.f, 0.f, 0.f, 0.f};
            acc[nt] = MFMA16(A[nt][0].v, B[0].v, acc[nt]);
            acc[nt] = MFMA16(A[nt][1].v, B[1].v, acc[nt]);
        }
        float ps0 = 0.f, ps1 = 0.f, pd0 = 0.f, pd1 = 0.f;
        bool ok = (rb + m) < n;
        #pragma unroll
        for (int nt = 0; nt < 8; ++nt) {
            float4 asv = *(const float4*)(att_src + nt * 16 + q * 4);
            float4 adv = *(const float4*)(att_dst + nt * 16 + q * 4);
            f32x4 d = acc[nt];
            H4 pk;
            pk.h2[0] = __floats2half2_rn(d[0], d[1]);
            pk.h2[1] = __floats2half2_rn(d[2], d[3]);
            if (ok) *(uint2*)(xl + (size_t)(rb + m) * 128 + nt * 16 + q * 4) = pk.u;
            float cs = d[0] * asv.x + d[1] * asv.y + d[2] * asv.z + d[3] * asv.w;
            float cd = d[0] * adv.x + d[1] * adv.y + d[2] * adv.z + d[3] * adv.w;
            if (nt < 4) { ps0 += cs; pd0 += cd; } else { ps1 += cs; pd1 += cd; }
        }
        ps0 += __shfl_xor(ps0, 16, 64); ps0 += __shfl_xor(ps0, 32, 64);
        ps1 += __shfl_xor(ps1, 16, 64); ps1 += __shfl_xor(ps1, 32, 64);
        pd0 += __shfl_xor(pd0, 16, 64); pd0 += __shfl_xor(pd0, 32, 64);
        pd1 += __shfl_xor(pd1, 16, 64); pd1 += __shfl_xor(pd1, 32, 64);
        if (lane < 16 && ok) {
            *(float2*)(a_src + (size_t)(rb + m) * 2) = make_float2(ps0, ps1);
            *(float2*)(a_dst + (size_t)(rb + m) * 2) = make_float2(pd0, pd1);
        }
    }
}

// ---------- layer-2: xl = elu(gat)@Wf + bf (fp16 out) + a_src/a_dst ----------
__global__ __launch_bounds__(256, 2) void k_mm_att2(
    const float* __restrict__ g, const __half* __restrict__ wft, const float* __restrict__ bf,
    const float* __restrict__ att_src, const float* __restrict__ att_dst,
    __half* __restrict__ xl, float* __restrict__ a_src, float* __restrict__ a_dst,
    int n, int ntiles, int nwaves)
{
    int lane = threadIdx.x & 63;
    int wid = blockIdx.x * 4 + (threadIdx.x >> 6);
    int m = lane & 15, q = lane >> 4;

    H8 A[8][4];
    #pragma unroll
    for (int nt = 0; nt < 8; ++nt)
        #pragma unroll
        for (int kt = 0; kt < 4; ++kt)
            A[nt][kt].u = *(const uint4*)(wft + (size_t)(nt * 16 + m) * 128 + kt * 32 + q * 8);

    for (int t = wid; t < ntiles; t += nwaves) {
        int rb = t * 16;
        int row = rb + m; if (row >= n) row = n - 1;
        H8 B[4];
        #pragma unroll
        for (int kt = 0; kt < 4; ++kt) {
            const float4* p = (const float4*)(g + (size_t)row * 128 + kt * 32 + q * 8);
            float4 p0 = p[0], p1 = p[1];
            B[kt].h2[0] = __floats2half2_rn(elu1(p0.x), elu1(p0.y));
            B[kt].h2[1] = __floats2half2_rn(elu1(p0.z), elu1(p0.w));
            B[kt].h2[2] = __floats2half2_rn(elu1(p1.x), elu1(p1.y));
            B[kt].h2[3] = __floats2half2_rn(elu1(p1.z), elu1(p1.w));
        }
        f32x4 acc[8];
        #pragma unroll
        for (int nt = 0; nt < 8; ++nt) {
            acc[nt] = {0.f, 0.f, 0.f, 0.f};
            #pragma unroll
            for (int kt = 0; kt < 4; ++kt)
                acc[nt] = MFMA16(A[nt][kt].v, B[kt].v, acc[nt]);
        }
        float ps0 = 0.f, ps1 = 0.f, pd0 = 0.f, pd1 = 0.f;
        bool ok = (rb + m) < n;
        #pragma unroll
        for (int nt = 0; nt < 8; ++nt) {
            float4 bfv = *(const float4*)(bf + nt * 16 + q * 4);
            float4 asv = *(const float4*)(att_src + nt * 16 + q * 4);
            float4 adv = *(const float4*)(att_dst + nt * 16 + q * 4);
            f32x4 d = acc[nt];
            d[0] += bfv.x; d[1] += bfv.y; d[2] += bfv.z; d[3] += bfv.w;
            H4 pk;
            pk.h2[0] = __floats2half2_rn(d[0], d[1]);
            pk.h2[1] = __floats2half2_rn(d[2], d[3]);
            if (ok) *(uint2*)(xl + (size_t)(rb + m) * 128 + nt * 16 + q * 4) = pk.u;
            float cs = d[0] * asv.x + d[1] * asv.y + d[2] * asv.z + d[3] * asv.w;
            float cd = d[0] * adv.x + d[1] * adv.y + d[2] * adv.z + d[3] * adv.w;
            if (nt < 4) { ps0 += cs; pd0 += cd; } else { ps1 += cs; pd1 += cd; }
        }
        ps0 += __shfl_xor(ps0, 16, 64); ps0 += __shfl_xor(ps0, 32, 64);
        ps1 += __shfl_xor(ps1, 16, 64); ps1 += __shfl_xor(ps1, 32, 64);
        pd0 += __shfl_xor(pd0, 16, 64); pd0 += __shfl_xor(pd0, 32, 64);
        pd1 += __shfl_xor(pd1, 16, 64); pd1 += __shfl_xor(pd1, 32, 64);
        if (lane < 16 && ok) {
            *(float2*)(a_src + (size_t)(rb + m) * 2) = make_float2(ps0, ps1);
            *(float2*)(a_dst + (size_t)(rb + m) * 2) = make_float2(pd0, pd1);
        }
    }
}

// ---------- gather: 1 wave/dst, 4 edges/iter, fp16 xl ----------
__global__ __launch_bounds__(256, 4) void k_gather(
    const int* __restrict__ offs, const int* __restrict__ csr_src, int E_,
    const __half* __restrict__ xl, const float* __restrict__ a_src,
    const float* __restrict__ a_dst, const float* __restrict__ bias,
    float* __restrict__ out, int n)
{
    int t = threadIdx.x;
    int lane = t & 63;
    int d = blockIdx.x * 4 + (t >> 6);
    if (d >= n) return;
    int eh = lane >> 4;
    int cq = lane & 15;
    int h = cq >> 3;
    float ad = a_dst[d * 2 + h];
    const float4* bp = (const float4*)(bias + cq * 8);
    float4 b0 = bp[0], b1 = bp[1];
    int start = offs[d];
    int end = (d + 1 < n) ? offs[d + 1] : E_;
    float acc[8] = {0.f, 0.f, 0.f, 0.f, 0.f, 0.f, 0.f, 0.f};
    float den = 0.f;
    for (int j0 = start; j0 < end; j0 += 4) {
        int j = j0 + eh;
        bool valid = j < end;
        int s = valid ? csr_src[j] : d;
        float a = a_src[s * 2 + h] + ad;
        a = (a >= 0.f) ? a : NEG_SLOPE * a;
        float w = valid ? __expf(a) : 0.f;
        float4 raw = *(const float4*)(xl + (size_t)s * 128 + cq * 8);
        __half2* hp = (__half2*)&raw;
        float2 f0 = __half22float2(hp[0]);
        float2 f1 = __half22float2(hp[1]);
        float2 f2 = __half22float2(hp[2]);
        float2 f3 = __half22float2(hp[3]);
        acc[0] = fmaf(w, f0.x, acc[0]); acc[1] = fmaf(w, f0.y, acc[1]);
        acc[2] = fmaf(w, f1.x, acc[2]); acc[3] = fmaf(w, f1.y, acc[3]);
        acc[4] = fmaf(w, f2.x, acc[4]); acc[5] = fmaf(w, f2.y, acc[5]);
        acc[6] = fmaf(w, f3.x, acc[6]); acc[7] = fmaf(w, f3.y, acc[7]);
        den += w;
    }
    if (eh == 0) {
        float a = a_src[d * 2 + h] + ad;
        a = (a >= 0.f) ? a : NEG_SLOPE * a;
        float w = __expf(a);
        float4 raw = *(const float4*)(xl + (size_t)d * 128 + cq * 8);
        __half2* hp = (__half2*)&raw;
        float2 f0 = __half22float2(hp[0]);
        float2 f1 = __half22float2(hp[1]);
        float2 f2 = __half22float2(hp[2]);
        float2 f3 = __half22float2(hp[3]);
        acc[0] = fmaf(w, f0.x, acc[0]); acc[1] = fmaf(w, f0.y, acc[1]);
        acc[2] = fmaf(w, f1.x, acc[2]); acc[3] = fmaf(w, f1.y, acc[3]);
        acc[4] = fmaf(w, f2.x, acc[4]); acc[5] = fmaf(w, f2.y, acc[5]);
        acc[6] = fmaf(w, f3.x, acc[6]); acc[7] = fmaf(w, f3.y, acc[7]);
        den += w;
    }
    #pragma unroll
    for (int i = 0; i < 8; ++i) {
        acc[i] += __shfl_xor(acc[i], 16, 64);
        acc[i] += __shfl_xor(acc[i], 32, 64);
    }
    den += __shfl_xor(den, 16, 64);
    den += __shfl_xor(den, 32, 64);
    if (eh == 0) {
        float inv = 1.f / (den + 1e-16f);
        float4 o0 = make_float4(fmaf(acc[0], inv, b0.x), fmaf(acc[1], inv, b0.y),
                                fmaf(acc[2], inv, b0.z), fmaf(acc[3], inv, b0.w));
        float4 o1 = make_float4(fmaf(acc[4], inv, b1.x), fmaf(acc[5], inv, b1.y),
                                fmaf(acc[6], inv, b1.z), fmaf(acc[7], inv, b1.w));
        float4* op = (float4*)(out + (size_t)d * 128 + cq * 8);
        op[0] = o0; op[1] = o1;
    }
}

// ---------- head: softmax(elu(gat2)@Wfo + bfo + gumbel), MFMA ----------
__global__ __launch_bounds__(256, 2) void k_mm_final(
    const float* __restrict__ g, const __half* __restrict__ wfot, const float* __restrict__ bfo,
    const float* __restrict__ gu, float* __restrict__ out, int n, int ntiles, int nwaves)
{
    int lane = threadIdx.x & 63;
    int wid = blockIdx.x * 4 + (threadIdx.x >> 6);
    int m = lane & 15, q = lane >> 4;

    H8 A[2][4];
    #pragma unroll
    for (int nt = 0; nt < 2; ++nt)
        #pragma unroll
        for (int kt = 0; kt < 4; ++kt)
            A[nt][kt].u = *(const uint4*)(wfot + (size_t)(nt * 16 + m) * 128 + kt * 32 + q * 8);

    for (int t = wid; t < ntiles; t += nwaves) {
        int rb = t * 16;
        int row = rb + m; if (row >= n) row = n - 1;
        H8 B[4];
        #pragma unroll
        for (int kt = 0; kt < 4; ++kt) {
            const float4* p = (const float4*)(g + (size_t)row * 128 + kt * 32 + q * 8);
            float4 p0 = p[0], p1 = p[1];
            B[kt].h2[0] = __floats2half2_rn(elu1(p0.x), elu1(p0.y));
            B[kt].h2[1] = __floats2half2_rn(elu1(p0.z), elu1(p0.w));
            B[kt].h2[2] = __floats2half2_rn(elu1(p1.x), elu1(p1.y));
            B[kt].h2[3] = __floats2half2_rn(elu1(p1.z), elu1(p1.w));
        }
        f32x4 acc[2];
        #pragma unroll
        for (int nt = 0; nt < 2; ++nt) {
            acc[nt] = {0.f, 0.f, 0.f, 0.f};
            #pragma unroll
            for (int kt = 0; kt < 4; ++kt)
                acc[nt] = MFMA16(A[nt][kt].v, B[kt].v, acc[nt]);
        }
        float z[8];
        #pragma unroll
        for (int nt = 0; nt < 2; ++nt) {
            float4 bv = *(const float4*)(bfo + nt * 16 + q * 4);
            float4 uv = *(const float4*)(gu + (size_t)row * 32 + nt * 16 + q * 4);
            z[nt * 4 + 0] = acc[nt][0] + bv.x - __logf(-__logf(uv.x + 1e-20f) + 1e-20f);
            z[nt * 4 + 1] = acc[nt][1] + bv.y - __logf(-__logf(uv.y + 1e-20f) + 1e-20f);
            z[nt * 4 + 2] = acc[nt][2] + bv.z - __logf(-__logf(uv.z + 1e-20f) + 1e-20f);
            z[nt * 4 + 3] = acc[nt][3] + bv.w - __logf(-__logf(uv.w + 1e-20f) + 1e-20f);
        }
        float mx = z[0];
        #pragma unroll
        for (int i = 1; i < 8; ++i) mx = fmaxf(mx, z[i]);
        mx = fmaxf(mx, __shfl_xor(mx, 16, 64));
        mx = fmaxf(mx, __shfl_xor(mx, 32, 64));
        float sum = 0.f;
        #pragma unroll
        for (int i = 0; i < 8; ++i) { z[i] = __expf(z[i] - mx); sum += z[i]; }
        sum += __shfl_xor(sum, 16, 64);
        sum += __shfl_xor(sum, 32, 64);
        float inv = 1.f / sum;
        if (rb + m < n) {
            #pragma unroll
            for (int nt = 0; nt < 2; ++nt) {
                float4 o = make_float4(z[nt * 4 + 0] * inv, z[nt * 4 + 1] * inv,
                                       z[nt * 4 + 2] * inv, z[nt * 4 + 3] * inv);
                *(float4*)(out + (size_t)(rb + m) * 32 + nt * 16 + q * 4) = o;
            }
        }
    }
}

extern "C" void kernel_launch(void* const* d_in, const int* in_sizes, int n_in,
                              void* d_out, int out_size, void* d_ws, size_t ws_size,
                              hipStream_t stream) {
    const float* x        = (const float*)d_in[0];
    const int*   ei       = (const int*)  d_in[1];
    const float* W0       = (const float*)d_in[2];
    const float* att_src0 = (const float*)d_in[3];
    const float* att_dst0 = (const float*)d_in[4];
    const float* bias0    = (const float*)d_in[5];
    const float* fcw0     = (const float*)d_in[6];
    const float* fcb0     = (const float*)d_in[7];
    const float* W1       = (const float*)d_in[8];
    const float* att_src1 = (const float*)d_in[9];
    const float* att_dst1 = (const float*)d_in[10];
    const float* bias1    = (const float*)d_in[11];
    const float* fcw1     = (const float*)d_in[12];
    const float* fcb1     = (const float*)d_in[13];
    const float* out_w    = (const float*)d_in[14];
    const float* out_b    = (const float*)d_in[15];
    const float* gu       = (const float*)d_in[16];

    const int N_ = in_sizes[0] / INDIM;
    const int E_ = in_sizes[1] / 2;
    const int NB = (N_ + BW - 1) / BW;            // buckets (<= 512)

    float* ws = (float*)d_ws;
    size_t off = 0;
    __half* xl  = (__half*)(ws + off); off += (size_t)N_ * 64;
    float* gat   = ws + off; off += (size_t)N_ * FDIM;
    float* a_src = ws + off; off += (size_t)N_ * HEADS;
    float* a_dst = ws + off; off += (size_t)N_ * HEADS;
    __half* W0T  = (__half*)(ws + off); off += 128 * 64 / 2;
    __half* WfT  = (__half*)(ws + off); off += 128 * 128 / 2;
    __half* WfoT = (__half*)(ws + off); off += 32 * 128 / 2;
    float* bf    = ws + off; off += 128;
    float* bfo   = ws + off; off += 32;
    int* cnt     = (int*)(ws + off); off += (size_t)NB * NBLK;
    int* base    = (int*)(ws + off); off += (size_t)NB * NBLK;
    int* bstart  = (int*)(ws + off); off += NB + 1;
    int* offs    = (int*)(ws + off); off += N_;
    int* csr_src = (int*)(ws + off); off += E_;
    unsigned* ebuf = (unsigned*)(ws + off); off += E_;

    const int B = 256;
    dim3 blk(B);
    int g_gath = (N_ + 3) / 4;
    int ntiles = (N_ + 15) / 16;
    int GMM    = 384;
    int nwaves = GMM * 4;
    int epb    = (E_ + NBLK - 1) / NBLK;

    // ---- CSR build: two-pass radix (LDS atomics only) ----
    k_hist2    <<<NBLK, blk, 0, stream>>>(ei, E_, cnt, NB, epb);
    k_scanb    <<<1, dim3(512), 0, stream>>>(cnt, bstart, base, NB, E_);
    k_scatter2 <<<NBLK, blk, 0, stream>>>(ei, E_, base, ebuf, NB, epb);
    k_bfill    <<<NB, blk, 0, stream>>>(ebuf, bstart, offs, csr_src, N_);
    k_fuse_w   <<<322, dim3(128), 0, stream>>>(W0, fcw0, fcb0, W1, fcw1, fcb1, out_w, out_b,
                                               W0T, WfT, bf, WfoT, bfo);

    // ---- layer 1 ----
    k_mm_att1 <<<GMM,    blk, 0, stream>>>(x, W0T, att_src0, att_dst0, xl, a_src, a_dst,
                                           N_, ntiles, nwaves);
    k_gather  <<<g_gath, blk, 0, stream>>>(offs, csr_src, E_, xl, a_src, a_dst, bias0, gat, N_);

    // ---- layer 2 (fc0 fused via WfT) ----
    k_mm_att2 <<<GMM,    blk, 0, stream>>>(gat, WfT, bf, att_src1, att_dst1, xl, a_src, a_dst,
                                           N_, ntiles, nwaves);
    k_gather  <<<g_gath, blk, 0, stream>>>(offs, csr_src, E_, xl, a_src, a_dst, bias1, gat, N_);

    // ---- head (fc1 + out fused via WfoT) ----
    k_mm_final <<<GMM,   blk, 0, stream>>>(gat, WfoT, bfo, gu, (float*)d_out, N_, ntiles, nwaves);
}

// Round 7
// 257.043 us; speedup vs baseline: 3.2861x; 1.1555x over previous
//
#include <hip/hip_runtime.h>
#include <hip/hip_fp16.h>
#include <math.h>

#define HEADS 2
#define FDIM 128
#define INDIM 64
#define ODIM 32
#define NEG_SLOPE 0.2f
#define BSH 7                 // bucket = dst >> 7  (128 dsts/bucket)
#define BW  128
#define NBLK 128              // radix pass blocks

typedef _Float16 f16x8 __attribute__((ext_vector_type(8)));
typedef float f32x4 __attribute__((ext_vector_type(4)));
union H8 { uint4 u; f16x8 v; __half2 h2[4]; };
union H4 { uint2 u; __half2 h2[2]; };

__device__ __forceinline__ float elu1(float v) { return v > 0.f ? v : __expf(v) - 1.f; }

#define MFMA16(a, b, c) __builtin_amdgcn_mfma_f32_16x16x32_f16((a), (b), (c), 0, 0, 0)

// ---------------- CSR build: two-pass radix by bucket, LDS-atomics only ----------------
// cnt/base layout: [blk][bucket] -> index blk*nb + b  (coalesced in k_scanb over b)
__global__ __launch_bounds__(256) void k_hist2(const int* __restrict__ ei, int E_,
                                               int* __restrict__ cnt, int nb, int epb) {
    __shared__ int h[512];
    int t = threadIdx.x, blk = blockIdx.x;
    for (int i = t; i < nb; i += 256) h[i] = 0;
    __syncthreads();
    int e0 = blk * epb, e1 = min(E_, e0 + epb);
    for (int e = e0 + t; e < e1; e += 256)
        atomicAdd(&h[ei[E_ + e] >> BSH], 1);
    __syncthreads();
    for (int i = t; i < nb; i += 256) cnt[blk * nb + i] = h[i];
}

// scan: bucket totals -> bstart (exclusive), running bases base[blk][b]
__global__ __launch_bounds__(512) void k_scanb(const int* __restrict__ cnt,
                                               int* __restrict__ bstart,
                                               int* __restrict__ base, int nb, int E_) {
    __shared__ int sc[512];
    int t = threadIdx.x;
    int tot = 0;
    if (t < nb)
        for (int k = 0; k < NBLK; ++k) tot += cnt[k * nb + t];   // coalesced over t
    sc[t] = tot;
    __syncthreads();
    for (int o = 1; o < 512; o <<= 1) {
        int add = (t >= o) ? sc[t - o] : 0;
        __syncthreads();
        sc[t] += add;
        __syncthreads();
    }
    int ex = sc[t] - tot;
    if (t < nb) {
        bstart[t] = ex;
        int run = ex;
        for (int k = 0; k < NBLK; ++k) {
            base[k * nb + t] = run;                              // coalesced over t
            run += cnt[k * nb + t];
        }
    }
    if (t == 0) bstart[nb] = E_;
}

// pass 2: place edges; LDS frontier counters seeded from base[blk][b]
__global__ __launch_bounds__(256) void k_scatter2(const int* __restrict__ ei, int E_,
                                                  const int* __restrict__ base,
                                                  unsigned* __restrict__ ebuf,
                                                  int nb, int epb) {
    __shared__ int pcur[512];
    int t = threadIdx.x, blk = blockIdx.x;
    for (int i = t; i < nb; i += 256) pcur[i] = base[blk * nb + i];
    __syncthreads();
    int e0 = blk * epb, e1 = min(E_, e0 + epb);
    for (int e = e0 + t; e < e1; e += 256) {
        int s = ei[e], d = ei[E_ + e];
        int slot = atomicAdd(&pcur[d >> BSH], 1);
        ebuf[slot] = ((unsigned)(d & (BW - 1)) << 25) | (unsigned)s;
    }
}

// one block per bucket: LDS hist+scan of 128 local dsts -> offs + ranked fill
__global__ __launch_bounds__(256) void k_bfill(const unsigned* __restrict__ ebuf,
                                               const int* __restrict__ bstart,
                                               int* __restrict__ offs,
                                               int* __restrict__ csr_src, int n) {
    __shared__ int hist[BW], sc[BW], pcur[BW];
    int b = blockIdx.x;
    int t = threadIdx.x;
    int base_ = bstart[b];
    int cnt = bstart[b + 1] - base_;
    int d0 = b << BSH;
    if (t < BW) hist[t] = 0;
    __syncthreads();
    for (int i = t; i < cnt; i += 256)
        atomicAdd(&hist[ebuf[base_ + i] >> 25], 1);
    __syncthreads();
    int v = (t < BW) ? hist[t] : 0;
    if (t < BW) sc[t] = v;
    __syncthreads();
    for (int o = 1; o < BW; o <<= 1) {
        int add = (t < BW && t >= o) ? sc[t - o] : 0;
        __syncthreads();
        if (t < BW) sc[t] += add;
        __syncthreads();
    }
    if (t < BW) {
        int abspos = base_ + sc[t] - v;   // exclusive
        pcur[t] = abspos;
        if (d0 + t < n) offs[d0 + t] = abspos;
    }
    __syncthreads();
    for (int i = t; i < cnt; i += 256) {
        unsigned u = ebuf[base_ + i];
        int slot = atomicAdd(&pcur[u >> 25], 1);
        csr_src[slot] = (int)(u & 0x1FFFFFFu);
    }
}

// ---------- weight precompute ----------
__global__ __launch_bounds__(128) void k_fuse_w(
    const float* __restrict__ W0,
    const float* __restrict__ fcw0, const float* __restrict__ fcb0, const float* __restrict__ W1,
    const float* __restrict__ fcw1, const float* __restrict__ fcb1,
    const float* __restrict__ out_w, const float* __restrict__ out_b,
    __half* __restrict__ W0T, __half* __restrict__ WfT, float* __restrict__ bf,
    __half* __restrict__ WfoT, float* __restrict__ bfo)
{
    int b = blockIdx.x, c = threadIdx.x;
    if (b < 128) {
        float acc = 0.f;
        for (int j = 0; j < 64; ++j) acc = fmaf(fcw0[b * 64 + j], W1[j * 128 + c], acc);
        WfT[c * 128 + b] = __float2half(acc);
    } else if (b == 128) {
        float acc = 0.f;
        for (int j = 0; j < 64; ++j) acc = fmaf(fcb0[j], W1[j * 128 + c], acc);
        bf[c] = acc;
    } else if (b < 257) {
        int k = b - 129;
        if (c < 32) {
            float acc = 0.f;
            for (int j = 0; j < 64; ++j) acc = fmaf(fcw1[k * 64 + j], out_w[j * 32 + c], acc);
            WfoT[c * 128 + k] = __float2half(acc);
        }
    } else if (b == 257) {
        if (c < 32) {
            float acc = 0.f;
            for (int j = 0; j < 64; ++j) acc = fmaf(fcb1[j], out_w[j * 32 + c], acc);
            bfo[c] = acc + out_b[c];
        }
    } else {
        int k = b - 258;
        W0T[c * 64 + k] = __float2half(W0[k * 128 + c]);
    }
}

// ---------- layer-1: xl = x@W0 (fp16 out) + a_src/a_dst, MFMA ----------
__global__ __launch_bounds__(256, 2) void k_mm_att1(
    const float* __restrict__ x, const __half* __restrict__ w0t,
    const float* __restrict__ att_src, const float* __restrict__ att_dst,
    __half* __restrict__ xl, float* __restrict__ a_src, float* __restrict__ a_dst,
    int n, int ntiles, int nwaves)
{
    int lane = threadIdx.x & 63;
    int wid = blockIdx.x * 4 + (threadIdx.x >> 6);
    int m = lane & 15, q = lane >> 4;

    H8 A[8][2];
    #pragma unroll
    for (int nt = 0; nt < 8; ++nt)
        #pragma unroll
        for (int kt = 0; kt < 2; ++kt)
            A[nt][kt].u = *(const uint4*)(w0t + (size_t)(nt * 16 + m) * 64 + kt * 32 + q * 8);

    for (int t = wid; t < ntiles; t += nwaves) {
        int rb = t * 16;
        int row = rb + m; if (row >= n) row = n - 1;
        H8 B[2];
        #pragma unroll
        for (int kt = 0; kt < 2; ++kt) {
            const float4* p = (const float4*)(x + (size_t)row * 64 + kt * 32 + q * 8);
            float4 p0 = p[0], p1 = p[1];
            B[kt].h2[0] = __floats2half2_rn(p0.x, p0.y);
            B[kt].h2[1] = __floats2half2_rn(p0.z, p0.w);
            B[kt].h2[2] = __floats2half2_rn(p1.x, p1.y);
            B[kt].h2[3] = __floats2half2_rn(p1.z, p1.w);
        }
        f32x4 acc[8];
        #pragma unroll
        for (int nt = 0; nt < 8; ++nt) {
            acc[nt] = {0.f, 0.f, 0.f, 0.f};
            acc[nt] = MFMA16(A[nt][0].v, B[0].v, acc[nt]);
            acc[nt] = MFMA16(A[nt][1].v, B[1].v, acc[nt]);
        }
        float ps0 = 0.f, ps1 = 0.f, pd0 = 0.f, pd1 = 0.f;
        bool ok = (rb + m) < n;
        #pragma unroll
        for (int nt = 0; nt < 8; ++nt) {
            float4 asv = *(const float4*)(att_src + nt * 16 + q * 4);
            float4 adv = *(const float4*)(att_dst + nt * 16 + q * 4);
            f32x4 d = acc[nt];
            H4 pk;
            pk.h2[0] = __floats2half2_rn(d[0], d[1]);
            pk.h2[1] = __floats2half2_rn(d[2], d[3]);
            if (ok) *(uint2*)(xl + (size_t)(rb + m) * 128 + nt * 16 + q * 4) = pk.u;
            float cs = d[0] * asv.x + d[1] * asv.y + d[2] * asv.z + d[3] * asv.w;
            float cd = d[0] * adv.x + d[1] * adv.y + d[2] * adv.z + d[3] * adv.w;
            if (nt < 4) { ps0 += cs; pd0 += cd; } else { ps1 += cs; pd1 += cd; }
        }
        ps0 += __shfl_xor(ps0, 16, 64); ps0 += __shfl_xor(ps0, 32, 64);
        ps1 += __shfl_xor(ps1, 16, 64); ps1 += __shfl_xor(ps1, 32, 64);
        pd0 += __shfl_xor(pd0, 16, 64); pd0 += __shfl_xor(pd0, 32, 64);
        pd1 += __shfl_xor(pd1, 16, 64); pd1 += __shfl_xor(pd1, 32, 64);
        if (lane < 16 && ok) {
            *(float2*)(a_src + (size_t)(rb + m) * 2) = make_float2(ps0, ps1);
            *(float2*)(a_dst + (size_t)(rb + m) * 2) = make_float2(pd0, pd1);
        }
    }
}

// ---------- layer-2: xl = elu(gat fp16)@Wf + bf (fp16 out) + a_src/a_dst ----------
__global__ __launch_bounds__(256, 2) void k_mm_att2(
    const __half* __restrict__ g, const __half* __restrict__ wft, const float* __restrict__ bf,
    const float* __restrict__ att_src, const float* __restrict__ att_dst,
    __half* __restrict__ xl, float* __restrict__ a_src, float* __restrict__ a_dst,
    int n, int ntiles, int nwaves)
{
    int lane = threadIdx.x & 63;
    int wid = blockIdx.x * 4 + (threadIdx.x >> 6);
    int m = lane & 15, q = lane >> 4;

    H8 A[8][4];
    #pragma unroll
    for (int nt = 0; nt < 8; ++nt)
        #pragma unroll
        for (int kt = 0; kt < 4; ++kt)
            A[nt][kt].u = *(const uint4*)(wft + (size_t)(nt * 16 + m) * 128 + kt * 32 + q * 8);

    for (int t = wid; t < ntiles; t += nwaves) {
        int rb = t * 16;
        int row = rb + m; if (row >= n) row = n - 1;
        H8 B[4];
        #pragma unroll
        for (int kt = 0; kt < 4; ++kt) {
            H8 raw;
            raw.u = *(const uint4*)(g + (size_t)row * 128 + kt * 32 + q * 8);
            #pragma unroll
            for (int r = 0; r < 4; ++r) {
                float2 f = __half22float2(raw.h2[r]);
                B[kt].h2[r] = __floats2half2_rn(elu1(f.x), elu1(f.y));
            }
        }
        f32x4 acc[8];
        #pragma unroll
        for (int nt = 0; nt < 8; ++nt) {
            acc[nt] = {0.f, 0.f, 0.f, 0.f};
            #pragma unroll
            for (int kt = 0; kt < 4; ++kt)
                acc[nt] = MFMA16(A[nt][kt].v, B[kt].v, acc[nt]);
        }
        float ps0 = 0.f, ps1 = 0.f, pd0 = 0.f, pd1 = 0.f;
        bool ok = (rb + m) < n;
        #pragma unroll
        for (int nt = 0; nt < 8; ++nt) {
            float4 bfv = *(const float4*)(bf + nt * 16 + q * 4);
            float4 asv = *(const float4*)(att_src + nt * 16 + q * 4);
            float4 adv = *(const float4*)(att_dst + nt * 16 + q * 4);
            f32x4 d = acc[nt];
            d[0] += bfv.x; d[1] += bfv.y; d[2] += bfv.z; d[3] += bfv.w;
            H4 pk;
            pk.h2[0] = __floats2half2_rn(d[0], d[1]);
            pk.h2[1] = __floats2half2_rn(d[2], d[3]);
            if (ok) *(uint2*)(xl + (size_t)(rb + m) * 128 + nt * 16 + q * 4) = pk.u;
            float cs = d[0] * asv.x + d[1] * asv.y + d[2] * asv.z + d[3] * asv.w;
            float cd = d[0] * adv.x + d[1] * adv.y + d[2] * adv.z + d[3] * adv.w;
            if (nt < 4) { ps0 += cs; pd0 += cd; } else { ps1 += cs; pd1 += cd; }
        }
        ps0 += __shfl_xor(ps0, 16, 64); ps0 += __shfl_xor(ps0, 32, 64);
        ps1 += __shfl_xor(ps1, 16, 64); ps1 += __shfl_xor(ps1, 32, 64);
        pd0 += __shfl_xor(pd0, 16, 64); pd0 += __shfl_xor(pd0, 32, 64);
        pd1 += __shfl_xor(pd1, 16, 64); pd1 += __shfl_xor(pd1, 32, 64);
        if (lane < 16 && ok) {
            *(float2*)(a_src + (size_t)(rb + m) * 2) = make_float2(ps0, ps1);
            *(float2*)(a_dst + (size_t)(rb + m) * 2) = make_float2(pd0, pd1);
        }
    }
}

// ---------- gather: 1 wave/dst, 8 edges in flight, fp16 xl in, fp16 out ----------
__global__ __launch_bounds__(256, 4) void k_gather(
    const int* __restrict__ offs, const int* __restrict__ csr_src, int E_,
    const __half* __restrict__ xl, const float* __restrict__ a_src,
    const float* __restrict__ a_dst, const float* __restrict__ bias,
    __half* __restrict__ out, int n)
{
    int t = threadIdx.x;
    int lane = t & 63;
    int d = blockIdx.x * 4 + (t >> 6);
    if (d >= n) return;
    int eh = lane >> 4;          // edge slot 0..3
    int cq = lane & 15;          // channels cq*8 .. cq*8+7
    int h = cq >> 3;
    float ad = a_dst[d * 2 + h];
    const float4* bp = (const float4*)(bias + cq * 8);
    float4 b0 = bp[0], b1 = bp[1];
    int start = offs[d];
    int end = (d + 1 < n) ? offs[d + 1] : E_;
    float acc[8] = {0.f, 0.f, 0.f, 0.f, 0.f, 0.f, 0.f, 0.f};
    float den = 0.f;
    for (int j0 = start; j0 < end; j0 += 8) {
        int ja = j0 + eh, jb = j0 + 4 + eh;
        bool va = ja < end, vb = jb < end;
        int sa = va ? csr_src[ja] : d;
        int sb = vb ? csr_src[jb] : d;
        float4 ra = *(const float4*)(xl + (size_t)sa * 128 + cq * 8);
        float4 rb = *(const float4*)(xl + (size_t)sb * 128 + cq * 8);
        float aa = a_src[sa * 2 + h] + ad;
        float ab = a_src[sb * 2 + h] + ad;
        aa = (aa >= 0.f) ? aa : NEG_SLOPE * aa;
        ab = (ab >= 0.f) ? ab : NEG_SLOPE * ab;
        float wa = va ? __expf(aa) : 0.f;
        float wb = vb ? __expf(ab) : 0.f;
        __half2* ha = (__half2*)&ra;
        __half2* hb = (__half2*)&rb;
        #pragma unroll
        for (int r = 0; r < 4; ++r) {
            float2 fa = __half22float2(ha[r]);
            float2 fb = __half22float2(hb[r]);
            acc[2 * r]     = fmaf(wa, fa.x, acc[2 * r]);
            acc[2 * r + 1] = fmaf(wa, fa.y, acc[2 * r + 1]);
            acc[2 * r]     = fmaf(wb, fb.x, acc[2 * r]);
            acc[2 * r + 1] = fmaf(wb, fb.y, acc[2 * r + 1]);
        }
        den += wa + wb;
    }
    if (eh == 0) {   // self-loop, counted once
        float a = a_src[d * 2 + h] + ad;
        a = (a >= 0.f) ? a : NEG_SLOPE * a;
        float w = __expf(a);
        float4 raw = *(const float4*)(xl + (size_t)d * 128 + cq * 8);
        __half2* hp = (__half2*)&raw;
        #pragma unroll
        for (int r = 0; r < 4; ++r) {
            float2 f = __half22float2(hp[r]);
            acc[2 * r]     = fmaf(w, f.x, acc[2 * r]);
            acc[2 * r + 1] = fmaf(w, f.y, acc[2 * r + 1]);
        }
        den += w;
    }
    #pragma unroll
    for (int i = 0; i < 8; ++i) {
        acc[i] += __shfl_xor(acc[i], 16, 64);
        acc[i] += __shfl_xor(acc[i], 32, 64);
    }
    den += __shfl_xor(den, 16, 64);
    den += __shfl_xor(den, 32, 64);
    if (eh == 0) {
        float inv = 1.f / (den + 1e-16f);
        H8 pk;
        pk.h2[0] = __floats2half2_rn(fmaf(acc[0], inv, b0.x), fmaf(acc[1], inv, b0.y));
        pk.h2[1] = __floats2half2_rn(fmaf(acc[2], inv, b0.z), fmaf(acc[3], inv, b0.w));
        pk.h2[2] = __floats2half2_rn(fmaf(acc[4], inv, b1.x), fmaf(acc[5], inv, b1.y));
        pk.h2[3] = __floats2half2_rn(fmaf(acc[6], inv, b1.z), fmaf(acc[7], inv, b1.w));
        *(uint4*)(out + (size_t)d * 128 + cq * 8) = pk.u;
    }
}

// ---------- head: softmax(elu(gat2 fp16)@Wfo + bfo + gumbel), MFMA ----------
__global__ __launch_bounds__(256, 2) void k_mm_final(
    const __half* __restrict__ g, const __half* __restrict__ wfot, const float* __restrict__ bfo,
    const float* __restrict__ gu, float* __restrict__ out, int n, int ntiles, int nwaves)
{
    int lane = threadIdx.x & 63;
    int wid = blockIdx.x * 4 + (threadIdx.x >> 6);
    int m = lane & 15, q = lane >> 4;

    H8 A[2][4];
    #pragma unroll
    for (int nt = 0; nt < 2; ++nt)
        #pragma unroll
        for (int kt = 0; kt < 4; ++kt)
            A[nt][kt].u = *(const uint4*)(wfot + (size_t)(nt * 16 + m) * 128 + kt * 32 + q * 8);

    for (int t = wid; t < ntiles; t += nwaves) {
        int rb = t * 16;
        int row = rb + m; if (row >= n) row = n - 1;
        H8 B[4];
        #pragma unroll
        for (int kt = 0; kt < 4; ++kt) {
            H8 raw;
            raw.u = *(const uint4*)(g + (size_t)row * 128 + kt * 32 + q * 8);
            #pragma unroll
            for (int r = 0; r < 4; ++r) {
                float2 f = __half22float2(raw.h2[r]);
                B[kt].h2[r] = __floats2half2_rn(elu1(f.x), elu1(f.y));
            }
        }
        f32x4 acc[2];
        #pragma unroll
        for (int nt = 0; nt < 2; ++nt) {
            acc[nt] = {0.f, 0.f, 0.f, 0.f};
            #pragma unroll
            for (int kt = 0; kt < 4; ++kt)
                acc[nt] = MFMA16(A[nt][kt].v, B[kt].v, acc[nt]);
        }
        float z[8];
        #pragma unroll
        for (int nt = 0; nt < 2; ++nt) {
            float4 bv = *(const float4*)(bfo + nt * 16 + q * 4);
            float4 uv = *(const float4*)(gu + (size_t)row * 32 + nt * 16 + q * 4);
            z[nt * 4 + 0] = acc[nt][0] + bv.x - __logf(-__logf(uv.x + 1e-20f) + 1e-20f);
            z[nt * 4 + 1] = acc[nt][1] + bv.y - __logf(-__logf(uv.y + 1e-20f) + 1e-20f);
            z[nt * 4 + 2] = acc[nt][2] + bv.z - __logf(-__logf(uv.z + 1e-20f) + 1e-20f);
            z[nt * 4 + 3] = acc[nt][3] + bv.w - __logf(-__logf(uv.w + 1e-20f) + 1e-20f);
        }
        float mx = z[0];
        #pragma unroll
        for (int i = 1; i < 8; ++i) mx = fmaxf(mx, z[i]);
        mx = fmaxf(mx, __shfl_xor(mx, 16, 64));
        mx = fmaxf(mx, __shfl_xor(mx, 32, 64));
        float sum = 0.f;
        #pragma unroll
        for (int i = 0; i < 8; ++i) { z[i] = __expf(z[i] - mx); sum += z[i]; }
        sum += __shfl_xor(sum, 16, 64);
        sum += __shfl_xor(sum, 32, 64);
        float inv = 1.f / sum;
        if (rb + m < n) {
            #pragma unroll
            for (int nt = 0; nt < 2; ++nt) {
                float4 o = make_float4(z[nt * 4 + 0] * inv, z[nt * 4 + 1] * inv,
                                       z[nt * 4 + 2] * inv, z[nt * 4 + 3] * inv);
                *(float4*)(out + (size_t)(rb + m) * 32 + nt * 16 + q * 4) = o;
            }
        }
    }
}

extern "C" void kernel_launch(void* const* d_in, const int* in_sizes, int n_in,
                              void* d_out, int out_size, void* d_ws, size_t ws_size,
                              hipStream_t stream) {
    const float* x        = (const float*)d_in[0];
    const int*   ei       = (const int*)  d_in[1];
    const float* W0       = (const float*)d_in[2];
    const float* att_src0 = (const float*)d_in[3];
    const float* att_dst0 = (const float*)d_in[4];
    const float* bias0    = (const float*)d_in[5];
    const float* fcw0     = (const float*)d_in[6];
    const float* fcb0     = (const float*)d_in[7];
    const float* W1       = (const float*)d_in[8];
    const float* att_src1 = (const float*)d_in[9];
    const float* att_dst1 = (const float*)d_in[10];
    const float* bias1    = (const float*)d_in[11];
    const float* fcw1     = (const float*)d_in[12];
    const float* fcb1     = (const float*)d_in[13];
    const float* out_w    = (const float*)d_in[14];
    const float* out_b    = (const float*)d_in[15];
    const float* gu       = (const float*)d_in[16];

    const int N_ = in_sizes[0] / INDIM;
    const int E_ = in_sizes[1] / 2;
    const int NB = (N_ + BW - 1) / BW;            // buckets (<= 512)

    float* ws = (float*)d_ws;
    size_t off = 0;
    __half* xl  = (__half*)(ws + off); off += (size_t)N_ * 64;
    __half* gat = (__half*)(ws + off); off += (size_t)N_ * 64;
    float* a_src = ws + off; off += (size_t)N_ * HEADS;
    float* a_dst = ws + off; off += (size_t)N_ * HEADS;
    __half* W0T  = (__half*)(ws + off); off += 128 * 64 / 2;
    __half* WfT  = (__half*)(ws + off); off += 128 * 128 / 2;
    __half* WfoT = (__half*)(ws + off); off += 32 * 128 / 2;
    float* bf    = ws + off; off += 128;
    float* bfo   = ws + off; off += 32;
    int* cnt     = (int*)(ws + off); off += (size_t)NB * NBLK;
    int* base    = (int*)(ws + off); off += (size_t)NB * NBLK;
    int* bstart  = (int*)(ws + off); off += NB + 1;
    int* offs    = (int*)(ws + off); off += N_;
    int* csr_src = (int*)(ws + off); off += E_;
    unsigned* ebuf = (unsigned*)(ws + off); off += E_;

    const int B = 256;
    dim3 blk(B);
    int g_gath = (N_ + 3) / 4;
    int ntiles = (N_ + 15) / 16;
    int GMM    = 384;
    int nwaves = GMM * 4;
    int epb    = (E_ + NBLK - 1) / NBLK;

    // ---- CSR build: two-pass radix (LDS atomics only) ----
    k_hist2    <<<NBLK, blk, 0, stream>>>(ei, E_, cnt, NB, epb);
    k_scanb    <<<1, dim3(512), 0, stream>>>(cnt, bstart, base, NB, E_);
    k_scatter2 <<<NBLK, blk, 0, stream>>>(ei, E_, base, ebuf, NB, epb);
    k_bfill    <<<NB, blk, 0, stream>>>(ebuf, bstart, offs, csr_src, N_);
    k_fuse_w   <<<322, dim3(128), 0, stream>>>(W0, fcw0, fcb0, W1, fcw1, fcb1, out_w, out_b,
                                               W0T, WfT, bf, WfoT, bfo);

    // ---- layer 1 ----
    k_mm_att1 <<<GMM,    blk, 0, stream>>>(x, W0T, att_src0, att_dst0, xl, a_src, a_dst,
                                           N_, ntiles, nwaves);
    k_gather  <<<g_gath, blk, 0, stream>>>(offs, csr_src, E_, xl, a_src, a_dst, bias0, gat, N_);

    // ---- layer 2 (fc0 fused via WfT) ----
    k_mm_att2 <<<GMM,    blk, 0, stream>>>(gat, WfT, bf, att_src1, att_dst1, xl, a_src, a_dst,
                                           N_, ntiles, nwaves);
    k_gather  <<<g_gath, blk, 0, stream>>>(offs, csr_src, E_, xl, a_src, a_dst, bias1, gat, N_);

    // ---- head (fc1 + out fused via WfoT) ----
    k_mm_final <<<GMM,   blk, 0, stream>>>(gat, WfoT, bfo, gu, (float*)d_out, N_, ntiles, nwaves);
}

// Round 8
// 250.620 us; speedup vs baseline: 3.3703x; 1.0256x over previous
//
#include <hip/hip_runtime.h>
#include <hip/hip_fp16.h>
#include <math.h>

#define HEADS 2
#define FDIM 128
#define INDIM 64
#define ODIM 32
#define NEG_SLOPE 0.2f
#define BSH 7                 // bucket = dst >> 7  (128 dsts/bucket)
#define BW  128
#define NBLK 128              // radix pass blocks

typedef _Float16 f16x8 __attribute__((ext_vector_type(8)));
typedef float f32x4 __attribute__((ext_vector_type(4)));
union H8 { uint4 u; f16x8 v; __half2 h2[4]; };
union H4 { uint2 u; __half2 h2[2]; };

__device__ __forceinline__ float elu1(float v) { return v > 0.f ? v : __expf(v) - 1.f; }

#define MFMA16(a, b, c) __builtin_amdgcn_mfma_f32_16x16x32_f16((a), (b), (c), 0, 0, 0)

// ---------------- CSR build: two-pass radix by bucket, LDS-atomics only ----------------
// cnt/base layout: [blk][bucket] -> index blk*nb + b  (coalesced in k_scanb over b)
__global__ __launch_bounds__(256) void k_hist2(const int* __restrict__ ei, int E_,
                                               int* __restrict__ cnt, int nb, int epb) {
    __shared__ int h[512];
    int t = threadIdx.x, blk = blockIdx.x;
    for (int i = t; i < nb; i += 256) h[i] = 0;
    __syncthreads();
    int e0 = blk * epb, e1 = min(E_, e0 + epb);
    for (int e = e0 + t; e < e1; e += 256)
        atomicAdd(&h[ei[E_ + e] >> BSH], 1);
    __syncthreads();
    for (int i = t; i < nb; i += 256) cnt[blk * nb + i] = h[i];
}

// scan: bucket totals -> bstart (exclusive), running bases base[blk][b]
__global__ __launch_bounds__(512) void k_scanb(const int* __restrict__ cnt,
                                               int* __restrict__ bstart,
                                               int* __restrict__ base, int nb, int E_) {
    __shared__ int sc[512];
    int t = threadIdx.x;
    int tot = 0;
    if (t < nb)
        for (int k = 0; k < NBLK; ++k) tot += cnt[k * nb + t];   // coalesced over t
    sc[t] = tot;
    __syncthreads();
    for (int o = 1; o < 512; o <<= 1) {
        int add = (t >= o) ? sc[t - o] : 0;
        __syncthreads();
        sc[t] += add;
        __syncthreads();
    }
    int ex = sc[t] - tot;
    if (t < nb) {
        bstart[t] = ex;
        int run = ex;
        for (int k = 0; k < NBLK; ++k) {
            base[k * nb + t] = run;                              // coalesced over t
            run += cnt[k * nb + t];
        }
    }
    if (t == 0) bstart[nb] = E_;
}

// pass 2: place edges; LDS frontier counters seeded from base[blk][b]
__global__ __launch_bounds__(256) void k_scatter2(const int* __restrict__ ei, int E_,
                                                  const int* __restrict__ base,
                                                  unsigned* __restrict__ ebuf,
                                                  int nb, int epb) {
    __shared__ int pcur[512];
    int t = threadIdx.x, blk = blockIdx.x;
    for (int i = t; i < nb; i += 256) pcur[i] = base[blk * nb + i];
    __syncthreads();
    int e0 = blk * epb, e1 = min(E_, e0 + epb);
    for (int e = e0 + t; e < e1; e += 256) {
        int s = ei[e], d = ei[E_ + e];
        int slot = atomicAdd(&pcur[d >> BSH], 1);
        ebuf[slot] = ((unsigned)(d & (BW - 1)) << 25) | (unsigned)s;
    }
}

// one block per bucket: LDS hist+scan of 128 local dsts -> offs + ranked fill
__global__ __launch_bounds__(256) void k_bfill(const unsigned* __restrict__ ebuf,
                                               const int* __restrict__ bstart,
                                               int* __restrict__ offs,
                                               int* __restrict__ csr_src, int n) {
    __shared__ int hist[BW], sc[BW], pcur[BW];
    int b = blockIdx.x;
    int t = threadIdx.x;
    int base_ = bstart[b];
    int cnt = bstart[b + 1] - base_;
    int d0 = b << BSH;
    if (t < BW) hist[t] = 0;
    __syncthreads();
    for (int i = t; i < cnt; i += 256)
        atomicAdd(&hist[ebuf[base_ + i] >> 25], 1);
    __syncthreads();
    int v = (t < BW) ? hist[t] : 0;
    if (t < BW) sc[t] = v;
    __syncthreads();
    for (int o = 1; o < BW; o <<= 1) {
        int add = (t < BW && t >= o) ? sc[t - o] : 0;
        __syncthreads();
        if (t < BW) sc[t] += add;
        __syncthreads();
    }
    if (t < BW) {
        int abspos = base_ + sc[t] - v;   // exclusive
        pcur[t] = abspos;
        if (d0 + t < n) offs[d0 + t] = abspos;
    }
    __syncthreads();
    for (int i = t; i < cnt; i += 256) {
        unsigned u = ebuf[base_ + i];
        int slot = atomicAdd(&pcur[u >> 25], 1);
        csr_src[slot] = (int)(u & 0x1FFFFFFu);
    }
}

// ---------- weight precompute ----------
__global__ __launch_bounds__(128) void k_fuse_w(
    const float* __restrict__ W0,
    const float* __restrict__ fcw0, const float* __restrict__ fcb0, const float* __restrict__ W1,
    const float* __restrict__ fcw1, const float* __restrict__ fcb1,
    const float* __restrict__ out_w, const float* __restrict__ out_b,
    __half* __restrict__ W0T, __half* __restrict__ WfT, float* __restrict__ bf,
    __half* __restrict__ WfoT, float* __restrict__ bfo)
{
    int b = blockIdx.x, c = threadIdx.x;
    if (b < 128) {
        float acc = 0.f;
        for (int j = 0; j < 64; ++j) acc = fmaf(fcw0[b * 64 + j], W1[j * 128 + c], acc);
        WfT[c * 128 + b] = __float2half(acc);
    } else if (b == 128) {
        float acc = 0.f;
        for (int j = 0; j < 64; ++j) acc = fmaf(fcb0[j], W1[j * 128 + c], acc);
        bf[c] = acc;
    } else if (b < 257) {
        int k = b - 129;
        if (c < 32) {
            float acc = 0.f;
            for (int j = 0; j < 64; ++j) acc = fmaf(fcw1[k * 64 + j], out_w[j * 32 + c], acc);
            WfoT[c * 128 + k] = __float2half(acc);
        }
    } else if (b == 257) {
        if (c < 32) {
            float acc = 0.f;
            for (int j = 0; j < 64; ++j) acc = fmaf(fcb1[j], out_w[j * 32 + c], acc);
            bfo[c] = acc + out_b[c];
        }
    } else {
        int k = b - 258;
        W0T[c * 64 + k] = __float2half(W0[k * 128 + c]);
    }
}

// ---------- layer-1: xl = x@W0 (fp16 out) + a_src/a_dst, MFMA ----------
__global__ __launch_bounds__(256, 2) void k_mm_att1(
    const float* __restrict__ x, const __half* __restrict__ w0t,
    const float* __restrict__ att_src, const float* __restrict__ att_dst,
    __half* __restrict__ xl, float* __restrict__ a_src, float* __restrict__ a_dst,
    int n, int ntiles, int nwaves)
{
    int lane = threadIdx.x & 63;
    int wid = blockIdx.x * 4 + (threadIdx.x >> 6);
    int m = lane & 15, q = lane >> 4;

    H8 A[8][2];
    #pragma unroll
    for (int nt = 0; nt < 8; ++nt)
        #pragma unroll
        for (int kt = 0; kt < 2; ++kt)
            A[nt][kt].u = *(const uint4*)(w0t + (size_t)(nt * 16 + m) * 64 + kt * 32 + q * 8);

    for (int t = wid; t < ntiles; t += nwaves) {
        int rb = t * 16;
        int row = rb + m; if (row >= n) row = n - 1;
        H8 B[2];
        #pragma unroll
        for (int kt = 0; kt < 2; ++kt) {
            const float4* p = (const float4*)(x + (size_t)row * 64 + kt * 32 + q * 8);
            float4 p0 = p[0], p1 = p[1];
            B[kt].h2[0] = __floats2half2_rn(p0.x, p0.y);
            B[kt].h2[1] = __floats2half2_rn(p0.z, p0.w);
            B[kt].h2[2] = __floats2half2_rn(p1.x, p1.y);
            B[kt].h2[3] = __floats2half2_rn(p1.z, p1.w);
        }
        f32x4 acc[8];
        #pragma unroll
        for (int nt = 0; nt < 8; ++nt) {
            acc[nt] = {0.f, 0.f, 0.f, 0.f};
            acc[nt] = MFMA16(A[nt][0].v, B[0].v, acc[nt]);
            acc[nt] = MFMA16(A[nt][1].v, B[1].v, acc[nt]);
        }
        float ps0 = 0.f, ps1 = 0.f, pd0 = 0.f, pd1 = 0.f;
        bool ok = (rb + m) < n;
        #pragma unroll
        for (int nt = 0; nt < 8; ++nt) {
            float4 asv = *(const float4*)(att_src + nt * 16 + q * 4);
            float4 adv = *(const float4*)(att_dst + nt * 16 + q * 4);
            f32x4 d = acc[nt];
            H4 pk;
            pk.h2[0] = __floats2half2_rn(d[0], d[1]);
            pk.h2[1] = __floats2half2_rn(d[2], d[3]);
            if (ok) *(uint2*)(xl + (size_t)(rb + m) * 128 + nt * 16 + q * 4) = pk.u;
            float cs = d[0] * asv.x + d[1] * asv.y + d[2] * asv.z + d[3] * asv.w;
            float cd = d[0] * adv.x + d[1] * adv.y + d[2] * adv.z + d[3] * adv.w;
            if (nt < 4) { ps0 += cs; pd0 += cd; } else { ps1 += cs; pd1 += cd; }
        }
        ps0 += __shfl_xor(ps0, 16, 64); ps0 += __shfl_xor(ps0, 32, 64);
        ps1 += __shfl_xor(ps1, 16, 64); ps1 += __shfl_xor(ps1, 32, 64);
        pd0 += __shfl_xor(pd0, 16, 64); pd0 += __shfl_xor(pd0, 32, 64);
        pd1 += __shfl_xor(pd1, 16, 64); pd1 += __shfl_xor(pd1, 32, 64);
        if (lane < 16 && ok) {
            *(float2*)(a_src + (size_t)(rb + m) * 2) = make_float2(ps0, ps1);
            *(float2*)(a_dst + (size_t)(rb + m) * 2) = make_float2(pd0, pd1);
        }
    }
}

// ---------- layer-2: xl = elu(gat fp16)@Wf + bf (fp16 out) + a_src/a_dst ----------
__global__ __launch_bounds__(256, 2) void k_mm_att2(
    const __half* __restrict__ g, const __half* __restrict__ wft, const float* __restrict__ bf,
    const float* __restrict__ att_src, const float* __restrict__ att_dst,
    __half* __restrict__ xl, float* __restrict__ a_src, float* __restrict__ a_dst,
    int n, int ntiles, int nwaves)
{
    int lane = threadIdx.x & 63;
    int wid = blockIdx.x * 4 + (threadIdx.x >> 6);
    int m = lane & 15, q = lane >> 4;

    H8 A[8][4];
    #pragma unroll
    for (int nt = 0; nt < 8; ++nt)
        #pragma unroll
        for (int kt = 0; kt < 4; ++kt)
            A[nt][kt].u = *(const uint4*)(wft + (size_t)(nt * 16 + m) * 128 + kt * 32 + q * 8);

    for (int t = wid; t < ntiles; t += nwaves) {
        int rb = t * 16;
        int row = rb + m; if (row >= n) row = n - 1;
        H8 B[4];
        #pragma unroll
        for (int kt = 0; kt < 4; ++kt) {
            H8 raw;
            raw.u = *(const uint4*)(g + (size_t)row * 128 + kt * 32 + q * 8);
            #pragma unroll
            for (int r = 0; r < 4; ++r) {
                float2 f = __half22float2(raw.h2[r]);
                B[kt].h2[r] = __floats2half2_rn(elu1(f.x), elu1(f.y));
            }
        }
        f32x4 acc[8];
        #pragma unroll
        for (int nt = 0; nt < 8; ++nt) {
            acc[nt] = {0.f, 0.f, 0.f, 0.f};
            #pragma unroll
            for (int kt = 0; kt < 4; ++kt)
                acc[nt] = MFMA16(A[nt][kt].v, B[kt].v, acc[nt]);
        }
        float ps0 = 0.f, ps1 = 0.f, pd0 = 0.f, pd1 = 0.f;
        bool ok = (rb + m) < n;
        #pragma unroll
        for (int nt = 0; nt < 8; ++nt) {
            float4 bfv = *(const float4*)(bf + nt * 16 + q * 4);
            float4 asv = *(const float4*)(att_src + nt * 16 + q * 4);
            float4 adv = *(const float4*)(att_dst + nt * 16 + q * 4);
            f32x4 d = acc[nt];
            d[0] += bfv.x; d[1] += bfv.y; d[2] += bfv.z; d[3] += bfv.w;
            H4 pk;
            pk.h2[0] = __floats2half2_rn(d[0], d[1]);
            pk.h2[1] = __floats2half2_rn(d[2], d[3]);
            if (ok) *(uint2*)(xl + (size_t)(rb + m) * 128 + nt * 16 + q * 4) = pk.u;
            float cs = d[0] * asv.x + d[1] * asv.y + d[2] * asv.z + d[3] * asv.w;
            float cd = d[0] * adv.x + d[1] * adv.y + d[2] * adv.z + d[3] * adv.w;
            if (nt < 4) { ps0 += cs; pd0 += cd; } else { ps1 += cs; pd1 += cd; }
        }
        ps0 += __shfl_xor(ps0, 16, 64); ps0 += __shfl_xor(ps0, 32, 64);
        ps1 += __shfl_xor(ps1, 16, 64); ps1 += __shfl_xor(ps1, 32, 64);
        pd0 += __shfl_xor(pd0, 16, 64); pd0 += __shfl_xor(pd0, 32, 64);
        pd1 += __shfl_xor(pd1, 16, 64); pd1 += __shfl_xor(pd1, 32, 64);
        if (lane < 16 && ok) {
            *(float2*)(a_src + (size_t)(rb + m) * 2) = make_float2(ps0, ps1);
            *(float2*)(a_dst + (size_t)(rb + m) * 2) = make_float2(pd0, pd1);
        }
    }
}

// ---------- gather v4: grid-stride, 8 edges in flight, v_pk_fma_f16 accumulate ----------
__global__ __launch_bounds__(256, 4) void k_gather(
    const int* __restrict__ offs, const int* __restrict__ csr_src, int E_,
    const __half* __restrict__ xl, const float* __restrict__ a_src,
    const float* __restrict__ a_dst, const float* __restrict__ bias,
    __half* __restrict__ out, int n, int ngrp)
{
    int t = threadIdx.x;
    int lane = t & 63;
    int eh = lane >> 4;          // edge slot 0..3
    int cq = lane & 15;          // channels cq*8 .. cq*8+7
    int h = cq >> 3;
    const float4* bp = (const float4*)(bias + cq * 8);
    float4 b0 = bp[0], b1 = bp[1];

    for (int grp = blockIdx.x; grp < ngrp; grp += gridDim.x) {
        int d = grp * 4 + (t >> 6);
        if (d >= n) continue;
        float ad = a_dst[d * 2 + h];
        int start = offs[d];
        int end = (d + 1 < n) ? offs[d + 1] : E_;
        __half2 hacc[4];
        #pragma unroll
        for (int r = 0; r < 4; ++r) hacc[r] = __floats2half2_rn(0.f, 0.f);
        float den = 0.f;
        for (int j0 = start; j0 < end; j0 += 8) {
            int ja = j0 + eh, jb = j0 + 4 + eh;
            bool va = ja < end, vb = jb < end;
            int sa = va ? csr_src[ja] : d;
            int sb = vb ? csr_src[jb] : d;
            H8 ra, rb;
            ra.u = *(const uint4*)(xl + (size_t)sa * 128 + cq * 8);
            rb.u = *(const uint4*)(xl + (size_t)sb * 128 + cq * 8);
            float aa = a_src[sa * 2 + h] + ad;
            float ab = a_src[sb * 2 + h] + ad;
            aa = (aa >= 0.f) ? aa : NEG_SLOPE * aa;
            ab = (ab >= 0.f) ? ab : NEG_SLOPE * ab;
            float wa = va ? __expf(aa) : 0.f;
            float wb = vb ? __expf(ab) : 0.f;
            __half2 wa2 = __floats2half2_rn(wa, wa);
            __half2 wb2 = __floats2half2_rn(wb, wb);
            #pragma unroll
            for (int r = 0; r < 4; ++r) {
                hacc[r] = __hfma2(ra.h2[r], wa2, hacc[r]);
                hacc[r] = __hfma2(rb.h2[r], wb2, hacc[r]);
            }
            den += wa + wb;
        }
        // unpack to fp32 for self-loop + reduction
        float acc[8];
        #pragma unroll
        for (int r = 0; r < 4; ++r) {
            float2 f = __half22float2(hacc[r]);
            acc[2 * r] = f.x; acc[2 * r + 1] = f.y;
        }
        if (eh == 0) {   // self-loop, counted once, fp32
            float a = a_src[d * 2 + h] + ad;
            a = (a >= 0.f) ? a : NEG_SLOPE * a;
            float w = __expf(a);
            H8 raw;
            raw.u = *(const uint4*)(xl + (size_t)d * 128 + cq * 8);
            #pragma unroll
            for (int r = 0; r < 4; ++r) {
                float2 f = __half22float2(raw.h2[r]);
                acc[2 * r]     = fmaf(w, f.x, acc[2 * r]);
                acc[2 * r + 1] = fmaf(w, f.y, acc[2 * r + 1]);
            }
            den += w;
        }
        #pragma unroll
        for (int i = 0; i < 8; ++i) {
            acc[i] += __shfl_xor(acc[i], 16, 64);
            acc[i] += __shfl_xor(acc[i], 32, 64);
        }
        den += __shfl_xor(den, 16, 64);
        den += __shfl_xor(den, 32, 64);
        if (eh == 0) {
            float inv = 1.f / (den + 1e-16f);
            H8 pk;
            pk.h2[0] = __floats2half2_rn(fmaf(acc[0], inv, b0.x), fmaf(acc[1], inv, b0.y));
            pk.h2[1] = __floats2half2_rn(fmaf(acc[2], inv, b0.z), fmaf(acc[3], inv, b0.w));
            pk.h2[2] = __floats2half2_rn(fmaf(acc[4], inv, b1.x), fmaf(acc[5], inv, b1.y));
            pk.h2[3] = __floats2half2_rn(fmaf(acc[6], inv, b1.z), fmaf(acc[7], inv, b1.w));
            *(uint4*)(out + (size_t)d * 128 + cq * 8) = pk.u;
        }
    }
}

// ---------- head: softmax(elu(gat2 fp16)@Wfo + bfo + gumbel), MFMA ----------
__global__ __launch_bounds__(256, 2) void k_mm_final(
    const __half* __restrict__ g, const __half* __restrict__ wfot, const float* __restrict__ bfo,
    const float* __restrict__ gu, float* __restrict__ out, int n, int ntiles, int nwaves)
{
    int lane = threadIdx.x & 63;
    int wid = blockIdx.x * 4 + (threadIdx.x >> 6);
    int m = lane & 15, q = lane >> 4;

    H8 A[2][4];
    #pragma unroll
    for (int nt = 0; nt < 2; ++nt)
        #pragma unroll
        for (int kt = 0; kt < 4; ++kt)
            A[nt][kt].u = *(const uint4*)(wfot + (size_t)(nt * 16 + m) * 128 + kt * 32 + q * 8);

    for (int t = wid; t < ntiles; t += nwaves) {
        int rb = t * 16;
        int row = rb + m; if (row >= n) row = n - 1;
        H8 B[4];
        #pragma unroll
        for (int kt = 0; kt < 4; ++kt) {
            H8 raw;
            raw.u = *(const uint4*)(g + (size_t)row * 128 + kt * 32 + q * 8);
            #pragma unroll
            for (int r = 0; r < 4; ++r) {
                float2 f = __half22float2(raw.h2[r]);
                B[kt].h2[r] = __floats2half2_rn(elu1(f.x), elu1(f.y));
            }
        }
        f32x4 acc[2];
        #pragma unroll
        for (int nt = 0; nt < 2; ++nt) {
            acc[nt] = {0.f, 0.f, 0.f, 0.f};
            #pragma unroll
            for (int kt = 0; kt < 4; ++kt)
                acc[nt] = MFMA16(A[nt][kt].v, B[kt].v, acc[nt]);
        }
        float z[8];
        #pragma unroll
        for (int nt = 0; nt < 2; ++nt) {
            float4 bv = *(const float4*)(bfo + nt * 16 + q * 4);
            float4 uv = *(const float4*)(gu + (size_t)row * 32 + nt * 16 + q * 4);
            z[nt * 4 + 0] = acc[nt][0] + bv.x - __logf(-__logf(uv.x + 1e-20f) + 1e-20f);
            z[nt * 4 + 1] = acc[nt][1] + bv.y - __logf(-__logf(uv.y + 1e-20f) + 1e-20f);
            z[nt * 4 + 2] = acc[nt][2] + bv.z - __logf(-__logf(uv.z + 1e-20f) + 1e-20f);
            z[nt * 4 + 3] = acc[nt][3] + bv.w - __logf(-__logf(uv.w + 1e-20f) + 1e-20f);
        }
        float mx = z[0];
        #pragma unroll
        for (int i = 1; i < 8; ++i) mx = fmaxf(mx, z[i]);
        mx = fmaxf(mx, __shfl_xor(mx, 16, 64));
        mx = fmaxf(mx, __shfl_xor(mx, 32, 64));
        float sum = 0.f;
        #pragma unroll
        for (int i = 0; i < 8; ++i) { z[i] = __expf(z[i] - mx); sum += z[i]; }
        sum += __shfl_xor(sum, 16, 64);
        sum += __shfl_xor(sum, 32, 64);
        float inv = 1.f / sum;
        if (rb + m < n) {
            #pragma unroll
            for (int nt = 0; nt < 2; ++nt) {
                float4 o = make_float4(z[nt * 4 + 0] * inv, z[nt * 4 + 1] * inv,
                                       z[nt * 4 + 2] * inv, z[nt * 4 + 3] * inv);
                *(float4*)(out + (size_t)(rb + m) * 32 + nt * 16 + q * 4) = o;
            }
        }
    }
}

extern "C" void kernel_launch(void* const* d_in, const int* in_sizes, int n_in,
                              void* d_out, int out_size, void* d_ws, size_t ws_size,
                              hipStream_t stream) {
    const float* x        = (const float*)d_in[0];
    const int*   ei       = (const int*)  d_in[1];
    const float* W0       = (const float*)d_in[2];
    const float* att_src0 = (const float*)d_in[3];
    const float* att_dst0 = (const float*)d_in[4];
    const float* bias0    = (const float*)d_in[5];
    const float* fcw0     = (const float*)d_in[6];
    const float* fcb0     = (const float*)d_in[7];
    const float* W1       = (const float*)d_in[8];
    const float* att_src1 = (const float*)d_in[9];
    const float* att_dst1 = (const float*)d_in[10];
    const float* bias1    = (const float*)d_in[11];
    const float* fcw1     = (const float*)d_in[12];
    const float* fcb1     = (const float*)d_in[13];
    const float* out_w    = (const float*)d_in[14];
    const float* out_b    = (const float*)d_in[15];
    const float* gu       = (const float*)d_in[16];

    const int N_ = in_sizes[0] / INDIM;
    const int E_ = in_sizes[1] / 2;
    const int NB = (N_ + BW - 1) / BW;            // buckets (<= 512)

    float* ws = (float*)d_ws;
    size_t off = 0;
    __half* xl  = (__half*)(ws + off); off += (size_t)N_ * 64;
    __half* gat = (__half*)(ws + off); off += (size_t)N_ * 64;
    float* a_src = ws + off; off += (size_t)N_ * HEADS;
    float* a_dst = ws + off; off += (size_t)N_ * HEADS;
    __half* W0T  = (__half*)(ws + off); off += 128 * 64 / 2;
    __half* WfT  = (__half*)(ws + off); off += 128 * 128 / 2;
    __half* WfoT = (__half*)(ws + off); off += 32 * 128 / 2;
    float* bf    = ws + off; off += 128;
    float* bfo   = ws + off; off += 32;
    int* cnt     = (int*)(ws + off); off += (size_t)NB * NBLK;
    int* base    = (int*)(ws + off); off += (size_t)NB * NBLK;
    int* bstart  = (int*)(ws + off); off += NB + 1;
    int* offs    = (int*)(ws + off); off += N_;
    int* csr_src = (int*)(ws + off); off += E_;
    unsigned* ebuf = (unsigned*)(ws + off); off += E_;

    const int B = 256;
    dim3 blk(B);
    int ngrp   = (N_ + 3) / 4;
    int g_gath = 2048;
    int ntiles = (N_ + 15) / 16;
    int GMM    = 384;
    int nwaves = GMM * 4;
    int epb    = (E_ + NBLK - 1) / NBLK;

    // ---- CSR build: two-pass radix (LDS atomics only) ----
    k_hist2    <<<NBLK, blk, 0, stream>>>(ei, E_, cnt, NB, epb);
    k_scanb    <<<1, dim3(512), 0, stream>>>(cnt, bstart, base, NB, E_);
    k_scatter2 <<<NBLK, blk, 0, stream>>>(ei, E_, base, ebuf, NB, epb);
    k_bfill    <<<NB, blk, 0, stream>>>(ebuf, bstart, offs, csr_src, N_);
    k_fuse_w   <<<322, dim3(128), 0, stream>>>(W0, fcw0, fcb0, W1, fcw1, fcb1, out_w, out_b,
                                               W0T, WfT, bf, WfoT, bfo);

    // ---- layer 1 ----
    k_mm_att1 <<<GMM,    blk, 0, stream>>>(x, W0T, att_src0, att_dst0, xl, a_src, a_dst,
                                           N_, ntiles, nwaves);
    k_gather  <<<g_gath, blk, 0, stream>>>(offs, csr_src, E_, xl, a_src, a_dst, bias0, gat, N_, ngrp);

    // ---- layer 2 (fc0 fused via WfT) ----
    k_mm_att2 <<<GMM,    blk, 0, stream>>>(gat, WfT, bf, att_src1, att_dst1, xl, a_src, a_dst,
                                           N_, ntiles, nwaves);
    k_gather  <<<g_gath, blk, 0, stream>>>(offs, csr_src, E_, xl, a_src, a_dst, bias1, gat, N_, ngrp);

    // ---- head (fc1 + out fused via WfoT) ----
    k_mm_final <<<GMM,   blk, 0, stream>>>(gat, WfoT, bfo, gu, (float*)d_out, N_, ntiles, nwaves);
}